// Round 7
// baseline (51507.098 us; speedup 1.0000x reference)
//
#include <hip/hip_runtime.h>

typedef float v2f __attribute__((ext_vector_type(2)));

#define T_STEPS 100000
#define HDIM 16
#define UDIM 7
#define HID 64
#define NCHUNK 1562   /* full 64-step chunks */
#define TAIL 32       /* 100000 - 1562*64 */

__device__ __forceinline__ float tanh_fast(float x) {
    float e = __expf(2.0f * x);
    return 1.0f - 2.0f * __builtin_amdgcn_rcpf(e + 1.0f);
}

__global__ __launch_bounds__(64) __attribute__((amdgpu_waves_per_eu(1, 1)))
void node_scan(const float* __restrict__ U,
               const float* __restrict__ W1, const float* __restrict__ b1,
               const float* __restrict__ W2, const float* __restrict__ b2,
               const float* __restrict__ W3, const float* __restrict__ b3,
               const float* __restrict__ wd, const float* __restrict__ bd,
               const float* __restrict__ wt, const float* __restrict__ bt,
               const float* __restrict__ wc, const float* __restrict__ bc,
               const float* __restrict__ h0,
               float* __restrict__ out)
{
    const int lane = threadIdx.x;            // 0..63
    const float dt = (float)(5.0 / 60.0);

    __shared__ __align__(16) float zbuf[HID];        // z1 / z2 broadcast
    __shared__ __align__(16) float ubuf[2 * 64 * 8]; // u chunks, rows padded to 8

    // ---------------- weight preload (registers) ----------------
    float w1h[16];                               // W1 row, h-part (init only)
#pragma unroll
    for (int j = 0; j < 16; ++j) w1h[j] = W1[lane * 23 + j];
    v2f W1up[3];
#pragma unroll
    for (int j = 0; j < 3; ++j) {
        W1up[j].x = W1[lane * 23 + 16 + 2 * j];
        W1up[j].y = W1[lane * 23 + 16 + 2 * j + 1];
    }
    const float W1u6 = W1[lane * 23 + 22];
    const float b1r = b1[lane];

    v2f W2r[32];
#pragma unroll
    for (int j = 0; j < 32; ++j) {
        W2r[j].x = W2[lane * 64 + 2 * j];
        W2r[j].y = W2[lane * 64 + 2 * j + 1];
    }
    const float b2r = b2[lane];

    // ---------------- M = W1h @ W3  (64x64, fp32, one-time) ----------------
    v2f Mr[32];
#pragma unroll
    for (int j = 0; j < 32; ++j) Mr[j] = (v2f){0.f, 0.f};
    for (int k = 0; k < 16; ++k) {
        const float w = w1h[k];
        const float* w3r = W3 + k * 64;
#pragma unroll
        for (int j = 0; j < 32; ++j) {
            v2f w3v = *(const v2f*)&w3r[2 * j];
            Mr[j] = __builtin_elementwise_fma((v2f){w, w}, w3v, Mr[j]);
        }
    }
    float m3dt = 0.f;                      // dt * (W1h . b3)
    for (int k = 0; k < 16; ++k) m3dt = fmaf(w1h[k], b3[k], m3dt);
    m3dt *= dt;

    // ---------------- readout functionals: c = W3^T w, per lane ------------
    // lane 0 -> delay (wd), lane 1 -> taxi (wt), lane 2 -> loglam (wc);
    // other lanes compute a harmless copy of wd's functional.
    const float* wsel = (lane == 1) ? wt : (lane == 2) ? wc : wd;
    const float bsel  = (lane == 1) ? bt[0] : (lane == 2) ? bc[0] : bd[0];
    v2f Cr[32];
#pragma unroll
    for (int j = 0; j < 32; ++j) Cr[j] = (v2f){0.f, 0.f};
    float rb = 0.f;                        // dt * (w . b3)
    float rstate = bsel;                   // r(0) = w . h0 + b
    for (int k = 0; k < 16; ++k) {
        const float w = wsel[k];
        const float* w3r = W3 + k * 64;
#pragma unroll
        for (int j = 0; j < 32; ++j) {
            v2f w3v = *(const v2f*)&w3r[2 * j];
            Cr[j] = __builtin_elementwise_fma((v2f){w, w}, w3v, Cr[j]);
        }
        rb = fmaf(w, b3[k], rb);
        rstate = fmaf(w, h0[k], rstate);
    }
    rb *= dt;

    // ---------------- state ----------------
    float A;                               // W1h . h(t)  (per-lane scalar)
    {
        float s0 = 0.f, s1 = 0.f;
#pragma unroll
        for (int k = 0; k < 8; ++k) {
            s0 = fmaf(w1h[2 * k],     h0[2 * k],     s0);
            s1 = fmaf(w1h[2 * k + 1], h0[2 * k + 1], s1);
        }
        A = s0 + s1;
    }
    float zacc = 0.f;                      // sum of z2[lane] over all steps

    // ---------------- first u chunk + pad zero ----------------
#pragma unroll
    for (int r = 0; r < UDIM; ++r) {
        int flat = r * 64 + lane;
        int s = flat / 7, c = flat % 7;
        ubuf[s * 8 + c] = U[flat];
    }
    ubuf[lane * 8 + 7] = 0.f;
    ubuf[512 + lane * 8 + 7] = 0.f;
    __syncthreads();

    // tmp = chunk 1 (global)
    float tmp[UDIM];
#pragma unroll
    for (int r = 0; r < UDIM; ++r) tmp[r] = U[448 + r * 64 + lane];

    // initial u-part accumulator for step 0: W1u.u(0) + b1
    float uacc;
    {
        float4 ua = *(const float4*)&ubuf[0];
        float4 ub = *(const float4*)&ubuf[4];
        v2f v0 = __builtin_elementwise_fma(W1up[0], (v2f){ua.x, ua.y}, (v2f){0.f, 0.f});
        v0 = __builtin_elementwise_fma(W1up[1], (v2f){ua.z, ua.w}, v0);
        v0 = __builtin_elementwise_fma(W1up[2], (v2f){ub.x, ub.y}, v0);
        uacc = v0.x + v0.y + fmaf(W1u6, ub.z, b1r);
    }

    // ---------------- one Euler step -------------------------------------
    auto step = [&](int t) {
        // ---- z1 = tanh(A + uacc) ----
        const float z1 = tanh_fast(A + uacc);
        zbuf[lane] = z1;
        // all-gather z1 (in-order DS pipe sees the write)
        float4 zz[16];
#pragma unroll
        for (int q = 0; q < 16; ++q) zz[q] = *(const float4*)&zbuf[q * 4];

        // next step's u (issued now, consumed at loop bottom)
        const int tn = t + 1;
        const int ub_off = ((tn >> 6) & 1) * 512 + (tn & 63) * 8;
        float4 una = *(const float4*)&ubuf[ub_off];
        float4 unb = *(const float4*)&ubuf[ub_off + 4];

        // ---- readout r(t): already in rstate (recurrence) ----
        if (lane < 3) out[lane * T_STEPS + t] = rstate;

        // ---- z2 = tanh(W2 @ z1 + b2), packed fp32 ----
        v2f c0 = {b2r, 0.f}, c1 = {0.f, 0.f}, c2 = {0.f, 0.f}, c3 = {0.f, 0.f};
#pragma unroll
        for (int q = 0; q < 8; ++q) {
            c0 = __builtin_elementwise_fma(W2r[q * 4 + 0], (v2f){zz[2 * q].x, zz[2 * q].y}, c0);
            c1 = __builtin_elementwise_fma(W2r[q * 4 + 1], (v2f){zz[2 * q].z, zz[2 * q].w}, c1);
            c2 = __builtin_elementwise_fma(W2r[q * 4 + 2], (v2f){zz[2 * q + 1].x, zz[2 * q + 1].y}, c2);
            c3 = __builtin_elementwise_fma(W2r[q * 4 + 3], (v2f){zz[2 * q + 1].z, zz[2 * q + 1].w}, c3);
        }
        v2f cs = (c0 + c1) + (c2 + c3);
        const float z2 = tanh_fast(cs.x + cs.y);
        zbuf[lane] = z2;
        zacc += z2;                       // h(T) accumulator, off critical path
        // all-gather z2
        float4 qq[16];
#pragma unroll
        for (int q = 0; q < 16; ++q) qq[q] = *(const float4*)&zbuf[q * 4];

        // ---- A' = A + dt*(M @ z2) + m3dt ; r' = r + dt*(C @ z2) + rb ----
        v2f m0 = {0.f, 0.f}, m1 = {0.f, 0.f}, m2 = {0.f, 0.f}, m3 = {0.f, 0.f};
        v2f d0 = {0.f, 0.f}, d1 = {0.f, 0.f}, d2 = {0.f, 0.f}, d3 = {0.f, 0.f};
#pragma unroll
        for (int q = 0; q < 8; ++q) {
            v2f e0 = {qq[2 * q].x, qq[2 * q].y};
            v2f e1 = {qq[2 * q].z, qq[2 * q].w};
            v2f e2 = {qq[2 * q + 1].x, qq[2 * q + 1].y};
            v2f e3 = {qq[2 * q + 1].z, qq[2 * q + 1].w};
            m0 = __builtin_elementwise_fma(Mr[q * 4 + 0], e0, m0);
            d0 = __builtin_elementwise_fma(Cr[q * 4 + 0], e0, d0);
            m1 = __builtin_elementwise_fma(Mr[q * 4 + 1], e1, m1);
            d1 = __builtin_elementwise_fma(Cr[q * 4 + 1], e1, d1);
            m2 = __builtin_elementwise_fma(Mr[q * 4 + 2], e2, m2);
            d2 = __builtin_elementwise_fma(Cr[q * 4 + 2], e2, d2);
            m3 = __builtin_elementwise_fma(Mr[q * 4 + 3], e3, m3);
            d3 = __builtin_elementwise_fma(Cr[q * 4 + 3], e3, d3);
        }
        v2f ms = (m0 + m1) + (m2 + m3);
        v2f ds = (d0 + d1) + (d2 + d3);
        A = fmaf(dt, ms.x + ms.y, A + m3dt);
        rstate = fmaf(dt, ds.x + ds.y, rstate + rb);

        // ---- next step's uacc ----
        v2f uv = __builtin_elementwise_fma(W1up[0], (v2f){una.x, una.y}, (v2f){0.f, 0.f});
        uv = __builtin_elementwise_fma(W1up[1], (v2f){una.z, una.w}, uv);
        uv = __builtin_elementwise_fma(W1up[2], (v2f){unb.x, unb.y}, uv);
        uacc = uv.x + uv.y + fmaf(W1u6, unb.z, b1r);
    };

    // ---------------- chunked scan ----------------
    for (int cb = 0; cb < NCHUNK; ++cb) {
        // commit tmp (chunk cb+1) BEFORE stepping (li=63's next-u read needs it)
        const int other = 512 * ((cb + 1) & 1);
#pragma unroll
        for (int r = 0; r < UDIM; ++r) {
            int flat = r * 64 + lane;
            int s = flat / 7, c = flat % 7;
            ubuf[other + s * 8 + c] = tmp[r];
        }
        // issue global loads for chunk cb+2 (clamped)
        const int base = (cb + 2) * 448;
#pragma unroll
        for (int r = 0; r < UDIM; ++r) {
            int idx = base + r * 64 + lane;
            if (idx > T_STEPS * UDIM - 1) idx = T_STEPS * UDIM - 1;
            tmp[r] = U[idx];
        }
        const int t0 = cb * 64;
        for (int li = 0; li < 64; ++li) step(t0 + li);
    }
    for (int li = 0; li < TAIL; ++li) step(NCHUNK * 64 + li);

    // ---------------- final state: h(T) = h0 + dt*W3@zacc + T*dt*b3 --------
    zbuf[lane] = zacc;
    float4 za[16];
#pragma unroll
    for (int q = 0; q < 16; ++q) za[q] = *(const float4*)&zbuf[q * 4];
    const int row = lane & 15;
    const float* w3r = W3 + row * 64;
    float h0a = 0.f, h1a = 0.f;
#pragma unroll
    for (int q = 0; q < 16; ++q) {
        h0a = fmaf(w3r[4 * q + 0], za[q].x, h0a);
        h1a = fmaf(w3r[4 * q + 1], za[q].y, h1a);
        h0a = fmaf(w3r[4 * q + 2], za[q].z, h0a);
        h1a = fmaf(w3r[4 * q + 3], za[q].w, h1a);
    }
    const float hT = h0[row] + dt * (h0a + h1a) + (float)T_STEPS * dt * b3[row];
    if (lane < HDIM) out[3 * T_STEPS + lane] = hT;
}

extern "C" void kernel_launch(void* const* d_in, const int* in_sizes, int n_in,
                              void* d_out, int out_size, void* d_ws, size_t ws_size,
                              hipStream_t stream) {
    const float* U  = (const float*)d_in[0];
    const float* W1 = (const float*)d_in[1];
    const float* b1 = (const float*)d_in[2];
    const float* W2 = (const float*)d_in[3];
    const float* b2 = (const float*)d_in[4];
    const float* W3 = (const float*)d_in[5];
    const float* b3 = (const float*)d_in[6];
    const float* wd = (const float*)d_in[7];
    const float* bd = (const float*)d_in[8];
    const float* wt = (const float*)d_in[9];
    const float* bt = (const float*)d_in[10];
    const float* wc = (const float*)d_in[11];
    const float* bc = (const float*)d_in[12];
    const float* h0 = (const float*)d_in[13];
    (void)in_sizes; (void)n_in; (void)out_size; (void)d_ws; (void)ws_size;

    node_scan<<<dim3(1), dim3(64), 0, stream>>>(U, W1, b1, W2, b2, W3, b3,
                                                wd, bd, wt, bt, wc, bc, h0,
                                                (float*)d_out);
}

// Round 8
// 46784.900 us; speedup vs baseline: 1.1009x; 1.1009x over previous
//
#include <hip/hip_runtime.h>

typedef float v2f __attribute__((ext_vector_type(2)));

#define T_STEPS 100000
#define UDIM 7
#define NCHUNK 1562   /* full 64-step chunks */
#define TAIL 32       /* 100000 - 1562*64 */

__device__ __forceinline__ float tanh_fast(float x) {
    float e = __expf(2.0f * x);
    return 1.0f - 2.0f * __builtin_amdgcn_rcpf(e + 1.0f);
}

template <int CTRL>
__device__ __forceinline__ int dpp_i(int src) {
    return __builtin_amdgcn_update_dpp(0, src, CTRL, 0xF, 0xF, true);
}

// within-row (16-lane) all-gather via DPP row rotations: 15 VALU insts.
// slot j holds the value from row-lane (i +/- j) mod 16 — exact order is
// discovered at init by running this same tree on (lane&15).
__device__ __forceinline__ void row_allgather(int* d, int v0) {
    d[0]  = v0;
    d[1]  = dpp_i<0x121>(d[0]);                      // row_ror:1
    d[2]  = dpp_i<0x122>(d[0]);  d[3]  = dpp_i<0x122>(d[1]);   // row_ror:2
    d[4]  = dpp_i<0x124>(d[0]);  d[5]  = dpp_i<0x124>(d[1]);   // row_ror:4
    d[6]  = dpp_i<0x124>(d[2]);  d[7]  = dpp_i<0x124>(d[3]);
    d[8]  = dpp_i<0x128>(d[0]);  d[9]  = dpp_i<0x128>(d[1]);   // row_ror:8
    d[10] = dpp_i<0x128>(d[2]);  d[11] = dpp_i<0x128>(d[3]);
    d[12] = dpp_i<0x128>(d[4]);  d[13] = dpp_i<0x128>(d[5]);
    d[14] = dpp_i<0x128>(d[6]);  d[15] = dpp_i<0x128>(d[7]);
}

__global__ __launch_bounds__(64) __attribute__((amdgpu_waves_per_eu(1, 1)))
void node_scan(const float* __restrict__ U,
               const float* __restrict__ W1, const float* __restrict__ b1,
               const float* __restrict__ W2, const float* __restrict__ b2,
               const float* __restrict__ W3, const float* __restrict__ b3,
               const float* __restrict__ wd, const float* __restrict__ bd,
               const float* __restrict__ wt, const float* __restrict__ bt,
               const float* __restrict__ wc, const float* __restrict__ bc,
               const float* __restrict__ h0,
               float* __restrict__ out)
{
    const int lane = threadIdx.x;            // 0..63, lane = 16*r + C
    const int r = lane >> 4;                 // row (0..3) = column block
    const int C = lane & 15;
    const float dt = (float)(5.0 / 60.0);

    __shared__ __align__(16) float zbuf[64];         // final-hT scatter only
    __shared__ __align__(16) float ubuf[2 * 64 * 8]; // u chunks, rows padded to 8
    __shared__ __align__(16) float Msh[64 * 64];     // M staging (init only)

    // ---------------- discover DPP slot->column mapping ----------------
    int col[16];
    {
        int gi[16];
        row_allgather(gi, C);
#pragma unroll
        for (int j = 0; j < 16; ++j) col[j] = (r << 4) + gi[j];
    }

    // ---------------- natural-row weights ----------------
    float w1h[16];
#pragma unroll
    for (int j = 0; j < 16; ++j) w1h[j] = W1[lane * 23 + j];
    v2f W1up[3];
#pragma unroll
    for (int j = 0; j < 3; ++j) {
        W1up[j].x = W1[lane * 23 + 16 + 2 * j];
        W1up[j].y = W1[lane * 23 + 17 + 2 * j];
    }
    const float W1u6 = W1[lane * 23 + 22];
    const float b1r = b1[lane];
    const float b2r = b2[lane];

    // ---------------- W2 partial slices (xor-d outputs, slot order) --------
    v2f W2p[4][8];
#pragma unroll
    for (int d = 0; d < 4; ++d) {
        const int orow = ((r ^ d) << 4) | C;
        const float* w2r = W2 + orow * 64;
#pragma unroll
        for (int a = 0; a < 8; ++a)
            W2p[d][a] = (v2f){ w2r[col[2 * a]], w2r[col[2 * a + 1]] };
    }

    // ---------------- M = W1h @ W3, staged via LDS ----------------
    for (int c = 0; c < 64; ++c) {
        float acc = 0.f;
#pragma unroll
        for (int k = 0; k < 16; ++k) acc = fmaf(w1h[k], W3[k * 64 + c], acc);
        Msh[lane * 64 + c] = acc;
    }
    __syncthreads();
    v2f Mp[4][8];
#pragma unroll
    for (int d = 0; d < 4; ++d) {
        const int orow = ((r ^ d) << 4) | C;
        const float* mr = Msh + orow * 64;
#pragma unroll
        for (int a = 0; a < 8; ++a)
            Mp[d][a] = (v2f){ mr[col[2 * a]], mr[col[2 * a + 1]] };
    }
    float m3dt = 0.f;                        // dt * (W1h-row-lane . b3)
#pragma unroll
    for (int k = 0; k < 16; ++k) m3dt = fmaf(w1h[k], b3[k], m3dt);
    m3dt *= dt;

    // ---------------- readout functional for column C ----------------
    const float* wsel = (C == 1) ? wt : (C == 2) ? wc : wd;
    const float bsel  = (C == 1) ? bt[0] : (C == 2) ? bc[0] : bd[0];
    v2f Crp[8];
#pragma unroll
    for (int a = 0; a < 8; ++a) {
        float c0 = 0.f, c1 = 0.f;
#pragma unroll
        for (int k = 0; k < 16; ++k) {
            c0 = fmaf(wsel[k], W3[k * 64 + col[2 * a]], c0);
            c1 = fmaf(wsel[k], W3[k * 64 + col[2 * a + 1]], c1);
        }
        Crp[a] = (v2f){c0, c1};
    }
    float rb = 0.f, rstate = bsel;
#pragma unroll
    for (int k = 0; k < 16; ++k) {
        rb = fmaf(wsel[k], b3[k], rb);
        rstate = fmaf(wsel[k], h0[k], rstate);   // r(0) = w.h0 + b
    }
    rb *= dt;

    // ---------------- state ----------------
    float A = 0.f;                           // W1h-row-lane . h(t)
#pragma unroll
    for (int k = 0; k < 16; ++k) A = fmaf(w1h[k], h0[k], A);
    float zacc = 0.f;                        // sum of z2[lane] over steps

    // ---------------- first u chunk + pad zero ----------------
#pragma unroll
    for (int q = 0; q < UDIM; ++q) {
        int flat = q * 64 + lane;
        int s = flat / 7, c = flat % 7;
        ubuf[s * 8 + c] = U[flat];
    }
    ubuf[lane * 8 + 7] = 0.f;
    ubuf[512 + lane * 8 + 7] = 0.f;
    __syncthreads();

    float tmp[UDIM];
#pragma unroll
    for (int q = 0; q < UDIM; ++q) tmp[q] = U[448 + q * 64 + lane];

    float uacc;
    {
        float4 ua = *(const float4*)&ubuf[0];
        float4 ub = *(const float4*)&ubuf[4];
        v2f v0 = __builtin_elementwise_fma(W1up[0], (v2f){ua.x, ua.y}, (v2f){0.f, 0.f});
        v0 = __builtin_elementwise_fma(W1up[1], (v2f){ua.z, ua.w}, v0);
        v0 = __builtin_elementwise_fma(W1up[2], (v2f){ub.x, ub.y}, v0);
        uacc = v0.x + v0.y + fmaf(W1u6, ub.z, b1r);
    }

    // ---------------- one Euler step -------------------------------------
    auto step = [&](int t) {
        // ---- z1 = tanh(A + uacc), distributed 1/lane (natural order) ----
        const float z1 = tanh_fast(A + uacc);
        int zi[16];
        row_allgather(zi, __float_as_int(z1));

        // next step's u (independent; issued early)
        const int tn = t + 1;
        const int ub_off = ((tn >> 6) & 1) * 512 + (tn & 63) * 8;
        float4 una = *(const float4*)&ubuf[ub_off];
        float4 unb = *(const float4*)&ubuf[ub_off + 4];

        v2f zs[8];
#pragma unroll
        for (int a = 0; a < 8; ++a)
            zs[a] = (v2f){ __int_as_float(zi[2 * a]), __int_as_float(zi[2 * a + 1]) };

        // ---- W2 block-partials: 4 dots of 16 (xor-d outputs) ----
        v2f q0 = {0.f, 0.f}, q1 = {0.f, 0.f}, q2 = {0.f, 0.f}, q3 = {0.f, 0.f};
#pragma unroll
        for (int a = 0; a < 8; ++a) {
            q0 = __builtin_elementwise_fma(W2p[0][a], zs[a], q0);
            q1 = __builtin_elementwise_fma(W2p[1][a], zs[a], q1);
            q2 = __builtin_elementwise_fma(W2p[2][a], zs[a], q2);
            q3 = __builtin_elementwise_fma(W2p[3][a], zs[a], q3);
        }
        float Q0 = b2r + q0.x + q0.y;
        float Q1 = q1.x + q1.y;
        float Q2 = q2.x + q2.y;
        float Q3 = q3.x + q3.y;
        // reduce-scatter: lane ends owning output `lane`
        Q0 += __shfl_xor(Q2, 32);
        Q1 += __shfl_xor(Q3, 32);
        Q0 += __shfl_xor(Q1, 16);
        const float z2 = tanh_fast(Q0);
        zacc += z2;

        // ---- z2 row all-gather ----
        int qi[16];
        row_allgather(qi, __float_as_int(z2));
        v2f ws[8];
#pragma unroll
        for (int a = 0; a < 8; ++a)
            ws[a] = (v2f){ __int_as_float(qi[2 * a]), __int_as_float(qi[2 * a + 1]) };

        // ---- M block-partials + readout partial ----
        v2f m0 = {0.f, 0.f}, m1 = {0.f, 0.f}, m2 = {0.f, 0.f}, m3 = {0.f, 0.f};
        v2f pc = {0.f, 0.f};
#pragma unroll
        for (int a = 0; a < 8; ++a) {
            m0 = __builtin_elementwise_fma(Mp[0][a], ws[a], m0);
            m1 = __builtin_elementwise_fma(Mp[1][a], ws[a], m1);
            m2 = __builtin_elementwise_fma(Mp[2][a], ws[a], m2);
            m3 = __builtin_elementwise_fma(Mp[3][a], ws[a], m3);
            pc = __builtin_elementwise_fma(Crp[a],   ws[a], pc);
        }
        float R0 = m0.x + m0.y;
        float R1 = m1.x + m1.y;
        float R2 = m2.x + m2.y;
        float R3 = m3.x + m3.y;
        R0 += __shfl_xor(R2, 32);
        R1 += __shfl_xor(R3, 32);
        R0 += __shfl_xor(R1, 16);
        float P = pc.x + pc.y;                 // readout allreduce (off chain)
        P += __shfl_xor(P, 32);
        P += __shfl_xor(P, 16);

        if (lane < 3) out[lane * T_STEPS + t] = rstate;   // r(t) pre-update
        A = fmaf(dt, R0, A + m3dt);                       // the recurrence
        rstate = fmaf(dt, P, rstate + rb);

        // ---- next step's uacc ----
        v2f uv = __builtin_elementwise_fma(W1up[0], (v2f){una.x, una.y}, (v2f){0.f, 0.f});
        uv = __builtin_elementwise_fma(W1up[1], (v2f){una.z, una.w}, uv);
        uv = __builtin_elementwise_fma(W1up[2], (v2f){unb.x, unb.y}, uv);
        uacc = uv.x + uv.y + fmaf(W1u6, unb.z, b1r);
    };

    // ---------------- chunked scan ----------------
    for (int cb = 0; cb < NCHUNK; ++cb) {
        const int other = 512 * ((cb + 1) & 1);
#pragma unroll
        for (int q = 0; q < UDIM; ++q) {
            int flat = q * 64 + lane;
            int s = flat / 7, c = flat % 7;
            ubuf[other + s * 8 + c] = tmp[q];
        }
        const int base = (cb + 2) * 448;
#pragma unroll
        for (int q = 0; q < UDIM; ++q) {
            int idx = base + q * 64 + lane;
            if (idx > T_STEPS * UDIM - 1) idx = T_STEPS * UDIM - 1;
            tmp[q] = U[idx];
        }
        const int t0 = cb * 64;
        for (int li = 0; li < 64; ++li) step(t0 + li);
    }
    for (int li = 0; li < TAIL; ++li) step(NCHUNK * 64 + li);

    // ---------------- final state: h(T) = h0 + dt*W3@zacc + T*dt*b3 --------
    zbuf[lane] = zacc;
    float4 za[16];
#pragma unroll
    for (int q = 0; q < 16; ++q) za[q] = *(const float4*)&zbuf[q * 4];
    const int row = lane & 15;
    const float* w3r = W3 + row * 64;
    float h0a = 0.f, h1a = 0.f;
#pragma unroll
    for (int q = 0; q < 16; ++q) {
        h0a = fmaf(w3r[4 * q + 0], za[q].x, h0a);
        h1a = fmaf(w3r[4 * q + 1], za[q].y, h1a);
        h0a = fmaf(w3r[4 * q + 2], za[q].z, h0a);
        h1a = fmaf(w3r[4 * q + 3], za[q].w, h1a);
    }
    const float hT = h0[row] + dt * (h0a + h1a) + (float)T_STEPS * dt * b3[row];
    if (lane < 16) out[3 * T_STEPS + lane] = hT;
}

extern "C" void kernel_launch(void* const* d_in, const int* in_sizes, int n_in,
                              void* d_out, int out_size, void* d_ws, size_t ws_size,
                              hipStream_t stream) {
    const float* U  = (const float*)d_in[0];
    const float* W1 = (const float*)d_in[1];
    const float* b1 = (const float*)d_in[2];
    const float* W2 = (const float*)d_in[3];
    const float* b2 = (const float*)d_in[4];
    const float* W3 = (const float*)d_in[5];
    const float* b3 = (const float*)d_in[6];
    const float* wd = (const float*)d_in[7];
    const float* bd = (const float*)d_in[8];
    const float* wt = (const float*)d_in[9];
    const float* bt = (const float*)d_in[10];
    const float* wc = (const float*)d_in[11];
    const float* bc = (const float*)d_in[12];
    const float* h0 = (const float*)d_in[13];
    (void)in_sizes; (void)n_in; (void)out_size; (void)d_ws; (void)ws_size;

    node_scan<<<dim3(1), dim3(64), 0, stream>>>(U, W1, b1, W2, b2, W3, b3,
                                                wd, bd, wt, bt, wc, bc, h0,
                                                (float*)d_out);
}

// Round 9
// 36396.652 us; speedup vs baseline: 1.4152x; 1.2854x over previous
//
#include <hip/hip_runtime.h>

typedef float v2f __attribute__((ext_vector_type(2)));

#define T_STEPS 100000
#define UDIM 7
#define NCHUNK 1562   /* full 64-step chunks */
#define TAIL 32       /* 100000 - 1562*64 */
#define ZSTR 66       /* zhist row stride: 8B-aligned, 2-way-bank-free */

__device__ __forceinline__ float tanh_fast(float x) {
    float e = __expf(2.0f * x);
    return 1.0f - 2.0f * __builtin_amdgcn_rcpf(e + 1.0f);
}

__device__ __forceinline__ float readlane_f(float v, int l) {
    return __int_as_float(__builtin_amdgcn_readlane(__float_as_int(v), l));
}

__global__ __launch_bounds__(64) __attribute__((amdgpu_waves_per_eu(1, 1)))
void node_scan(const float* __restrict__ U,
               const float* __restrict__ W1, const float* __restrict__ b1,
               const float* __restrict__ W2, const float* __restrict__ b2,
               const float* __restrict__ W3, const float* __restrict__ b3,
               const float* __restrict__ wd, const float* __restrict__ bd,
               const float* __restrict__ wt, const float* __restrict__ bt,
               const float* __restrict__ wc, const float* __restrict__ bc,
               const float* __restrict__ h0,
               float* __restrict__ out)
{
    const int lane = threadIdx.x;            // 0..63
    const float dt = (float)(5.0 / 60.0);

    __shared__ __align__(16) float zbuf[64];          // z1/z2 broadcast
    __shared__ __align__(16) float ubuf[2 * 64 * 8];  // u chunks, rows padded to 8
    __shared__ __align__(16) float zhist[64 * ZSTR];  // z2 history [step][comp]
    __shared__ __align__(16) float cbuf[3 * 64];      // readout functionals

    // ---------------- weight preload (registers) ----------------
    float w1h[16];
#pragma unroll
    for (int j = 0; j < 16; ++j) w1h[j] = W1[lane * 23 + j];
    v2f W1up[3];
#pragma unroll
    for (int j = 0; j < 3; ++j) {
        W1up[j].x = W1[lane * 23 + 16 + 2 * j];
        W1up[j].y = W1[lane * 23 + 17 + 2 * j];
    }
    const float W1u6 = W1[lane * 23 + 22];
    const float b1r = b1[lane];

    v2f W2r[32];
#pragma unroll
    for (int j = 0; j < 32; ++j) {
        W2r[j].x = W2[lane * 64 + 2 * j];
        W2r[j].y = W2[lane * 64 + 2 * j + 1];
    }
    const float b2r = b2[lane];

    // ---------------- M = W1h @ W3 (row `lane`, fp32, one-time) ------------
    v2f Mr[32];
#pragma unroll
    for (int j = 0; j < 32; ++j) Mr[j] = (v2f){0.f, 0.f};
    for (int k = 0; k < 16; ++k) {
        const float w = w1h[k];
        const float* w3r = W3 + k * 64;
#pragma unroll
        for (int j = 0; j < 32; ++j) {
            v2f w3v = *(const v2f*)&w3r[2 * j];
            Mr[j] = __builtin_elementwise_fma((v2f){w, w}, w3v, Mr[j]);
        }
    }
    float m3dt = 0.f;                        // dt * (W1h . b3)
    for (int k = 0; k < 16; ++k) m3dt = fmaf(w1h[k], b3[k], m3dt);
    m3dt *= dt;

    // ---------------- readout functionals c = W3^T w → LDS -----------------
    {
        float cd = 0.f, ct = 0.f, cc = 0.f;
        for (int k = 0; k < 16; ++k) {
            const float w3v = W3[k * 64 + lane];
            cd = fmaf(wd[k], w3v, cd);
            ct = fmaf(wt[k], w3v, ct);
            cc = fmaf(wc[k], w3v, cc);
        }
        cbuf[lane] = cd; cbuf[64 + lane] = ct; cbuf[128 + lane] = cc;
    }
    float rbD = 0.f, rbT = 0.f, rbC = 0.f;          // dt*(w.b3)
    float rchD = bd[0], rchT = bt[0], rchC = bc[0]; // r at chunk start
    for (int k = 0; k < 16; ++k) {
        rbD = fmaf(wd[k], b3[k], rbD);  rchD = fmaf(wd[k], h0[k], rchD);
        rbT = fmaf(wt[k], b3[k], rbT);  rchT = fmaf(wt[k], h0[k], rchT);
        rbC = fmaf(wc[k], b3[k], rbC);  rchC = fmaf(wc[k], h0[k], rchC);
    }
    rbD *= dt; rbT *= dt; rbC *= dt;

    // ---------------- state ----------------
    float A = 0.f;                           // W1h-row-lane . h(t)
    for (int k = 0; k < 16; ++k) A = fmaf(w1h[k], h0[k], A);
    float zacc = 0.f;

    // ---------------- first u chunk + pad zero ----------------
#pragma unroll
    for (int r = 0; r < UDIM; ++r) {
        int flat = r * 64 + lane;
        int s = flat / 7, c = flat % 7;
        ubuf[s * 8 + c] = U[flat];
    }
    ubuf[lane * 8 + 7] = 0.f;
    ubuf[512 + lane * 8 + 7] = 0.f;
    __syncthreads();

    float tmp[UDIM];
#pragma unroll
    for (int r = 0; r < UDIM; ++r) tmp[r] = U[448 + r * 64 + lane];

    float uacc;
    {
        float4 ua = *(const float4*)&ubuf[0];
        float4 ub = *(const float4*)&ubuf[4];
        v2f v0 = __builtin_elementwise_fma(W1up[0], (v2f){ua.x, ua.y}, (v2f){0.f, 0.f});
        v0 = __builtin_elementwise_fma(W1up[1], (v2f){ua.z, ua.w}, v0);
        v0 = __builtin_elementwise_fma(W1up[2], (v2f){ub.x, ub.y}, v0);
        uacc = v0.x + v0.y + fmaf(W1u6, ub.z, b1r);
    }

    // ---------------- one Euler step (no readout work in-loop) -------------
    auto step = [&](int t, int li) {
        // ---- z1 = tanh(A + uacc) ----
        const float z1 = tanh_fast(A + uacc);
        zbuf[lane] = z1;
        float4 zz[16];
#pragma unroll
        for (int q = 0; q < 16; ++q) zz[q] = *(const float4*)&zbuf[q * 4];

        // next step's u (independent; issued early)
        const int tn = t + 1;
        const int ub_off = ((tn >> 6) & 1) * 512 + (tn & 63) * 8;
        float4 una = *(const float4*)&ubuf[ub_off];
        float4 unb = *(const float4*)&ubuf[ub_off + 4];

        // ---- z2 = tanh(W2 @ z1 + b2) ----
        v2f c0 = {b2r, 0.f}, c1 = {0.f, 0.f}, c2 = {0.f, 0.f}, c3 = {0.f, 0.f};
#pragma unroll
        for (int q = 0; q < 8; ++q) {
            c0 = __builtin_elementwise_fma(W2r[q * 4 + 0], (v2f){zz[2 * q].x, zz[2 * q].y}, c0);
            c1 = __builtin_elementwise_fma(W2r[q * 4 + 1], (v2f){zz[2 * q].z, zz[2 * q].w}, c1);
            c2 = __builtin_elementwise_fma(W2r[q * 4 + 2], (v2f){zz[2 * q + 1].x, zz[2 * q + 1].y}, c2);
            c3 = __builtin_elementwise_fma(W2r[q * 4 + 3], (v2f){zz[2 * q + 1].z, zz[2 * q + 1].w}, c3);
        }
        v2f cs = (c0 + c1) + (c2 + c3);
        const float z2 = tanh_fast(cs.x + cs.y);
        zbuf[lane] = z2;
        float4 qq[16];
#pragma unroll
        for (int q = 0; q < 16; ++q) qq[q] = *(const float4*)&zbuf[q * 4];
        zhist[li * ZSTR + lane] = z2;      // history append (readouts batched)
        zacc += z2;

        // ---- A' = A + dt*(M @ z2) + m3dt ----
        v2f m0 = {0.f, 0.f}, m1 = {0.f, 0.f}, m2 = {0.f, 0.f}, m3 = {0.f, 0.f};
#pragma unroll
        for (int q = 0; q < 8; ++q) {
            m0 = __builtin_elementwise_fma(Mr[q * 4 + 0], (v2f){qq[2 * q].x, qq[2 * q].y}, m0);
            m1 = __builtin_elementwise_fma(Mr[q * 4 + 1], (v2f){qq[2 * q].z, qq[2 * q].w}, m1);
            m2 = __builtin_elementwise_fma(Mr[q * 4 + 2], (v2f){qq[2 * q + 1].x, qq[2 * q + 1].y}, m2);
            m3 = __builtin_elementwise_fma(Mr[q * 4 + 3], (v2f){qq[2 * q + 1].z, qq[2 * q + 1].w}, m3);
        }
        v2f ms = (m0 + m1) + (m2 + m3);
        A = fmaf(dt, ms.x + ms.y, A + m3dt);

        // ---- next step's uacc ----
        v2f uv = __builtin_elementwise_fma(W1up[0], (v2f){una.x, una.y}, (v2f){0.f, 0.f});
        uv = __builtin_elementwise_fma(W1up[1], (v2f){una.z, una.w}, uv);
        uv = __builtin_elementwise_fma(W1up[2], (v2f){unb.x, unb.y}, uv);
        uacc = uv.x + uv.y + fmaf(W1u6, unb.z, b1r);
    };

    // ---------------- batched readouts for one chunk (lane i ↔ step t0+i) --
    auto batch = [&](int t0) {
        const float* zr = &zhist[lane * ZSTR];
        v2f sd = {0.f, 0.f}, st = {0.f, 0.f}, sc = {0.f, 0.f};
#pragma unroll
        for (int q = 0; q < 32; ++q) {
            v2f zv = *(const v2f*)&zr[2 * q];
            sd = __builtin_elementwise_fma(*(const v2f*)&cbuf[2 * q],       zv, sd);
            st = __builtin_elementwise_fma(*(const v2f*)&cbuf[64 + 2 * q],  zv, st);
            sc = __builtin_elementwise_fma(*(const v2f*)&cbuf[128 + 2 * q], zv, sc);
        }
        float Sd = sd.x + sd.y, St = st.x + st.y, Sc = sc.x + sc.y;
        const float oD = Sd, oT = St, oC = Sc;
        // inclusive prefix scan over lanes (Hillis-Steele)
#pragma unroll
        for (int dl = 1; dl < 64; dl <<= 1) {
            float ud = __shfl_up(Sd, dl, 64);
            float ut = __shfl_up(St, dl, 64);
            float uc = __shfl_up(Sc, dl, 64);
            if (lane >= dl) { Sd += ud; St += ut; Sc += uc; }
        }
        const int t = t0 + lane;
        if (t < T_STEPS) {
            const float fl = (float)lane;
            out[t]               = fmaf(dt, Sd - oD, rchD) + fl * rbD;
            out[T_STEPS + t]     = fmaf(dt, St - oT, rchT) + fl * rbT;
            out[2 * T_STEPS + t] = fmaf(dt, Sc - oC, rchC) + fl * rbC;
        }
        rchD = fmaf(dt, readlane_f(Sd, 63), rchD) + 64.f * rbD;
        rchT = fmaf(dt, readlane_f(St, 63), rchT) + 64.f * rbT;
        rchC = fmaf(dt, readlane_f(Sc, 63), rchC) + 64.f * rbC;
    };

    // ---------------- chunked scan ----------------
    for (int cb = 0; cb < NCHUNK; ++cb) {
        const int other = 512 * ((cb + 1) & 1);
#pragma unroll
        for (int r = 0; r < UDIM; ++r) {
            int flat = r * 64 + lane;
            int s = flat / 7, c = flat % 7;
            ubuf[other + s * 8 + c] = tmp[r];
        }
        const int base = (cb + 2) * 448;
#pragma unroll
        for (int r = 0; r < UDIM; ++r) {
            int idx = base + r * 64 + lane;
            if (idx > T_STEPS * UDIM - 1) idx = T_STEPS * UDIM - 1;
            tmp[r] = U[idx];
        }
        const int t0 = cb * 64;
        for (int li = 0; li < 64; ++li) step(t0 + li, li);
        batch(t0);
    }
    for (int li = 0; li < TAIL; ++li) step(NCHUNK * 64 + li, li);
    batch(NCHUNK * 64);   // masked by t < T_STEPS

    // ---------------- final state: h(T) = h0 + dt*W3@zacc + T*dt*b3 --------
    zbuf[lane] = zacc;
    float4 za[16];
#pragma unroll
    for (int q = 0; q < 16; ++q) za[q] = *(const float4*)&zbuf[q * 4];
    const int row = lane & 15;
    const float* w3r = W3 + row * 64;
    float h0a = 0.f, h1a = 0.f;
#pragma unroll
    for (int q = 0; q < 16; ++q) {
        h0a = fmaf(w3r[4 * q + 0], za[q].x, h0a);
        h1a = fmaf(w3r[4 * q + 1], za[q].y, h1a);
        h0a = fmaf(w3r[4 * q + 2], za[q].z, h0a);
        h1a = fmaf(w3r[4 * q + 3], za[q].w, h1a);
    }
    const float hT = h0[row] + dt * (h0a + h1a) + (float)T_STEPS * dt * b3[row];
    if (lane < 16) out[3 * T_STEPS + lane] = hT;
}

extern "C" void kernel_launch(void* const* d_in, const int* in_sizes, int n_in,
                              void* d_out, int out_size, void* d_ws, size_t ws_size,
                              hipStream_t stream) {
    const float* U  = (const float*)d_in[0];
    const float* W1 = (const float*)d_in[1];
    const float* b1 = (const float*)d_in[2];
    const float* W2 = (const float*)d_in[3];
    const float* b2 = (const float*)d_in[4];
    const float* W3 = (const float*)d_in[5];
    const float* b3 = (const float*)d_in[6];
    const float* wd = (const float*)d_in[7];
    const float* bd = (const float*)d_in[8];
    const float* wt = (const float*)d_in[9];
    const float* bt = (const float*)d_in[10];
    const float* wc = (const float*)d_in[11];
    const float* bc = (const float*)d_in[12];
    const float* h0 = (const float*)d_in[13];
    (void)in_sizes; (void)n_in; (void)out_size; (void)d_ws; (void)ws_size;

    node_scan<<<dim3(1), dim3(64), 0, stream>>>(U, W1, b1, W2, b2, W3, b3,
                                                wd, bd, wt, bt, wc, bc, h0,
                                                (float*)d_out);
}

// Round 10
// 35303.287 us; speedup vs baseline: 1.4590x; 1.0310x over previous
//
#include <hip/hip_runtime.h>

typedef float v2f __attribute__((ext_vector_type(2)));

#define T_STEPS 100000
#define UDIM 7
#define NCHUNK 1562   /* full 64-step chunks */
#define TAIL 32       /* 100000 - 1562*64 */
#define ZSTR 68       /* zhist row stride (floats): 16B-aligned rows */

__device__ __forceinline__ float tanh_fast(float x) {
    float e = __expf(2.0f * x);
    return 1.0f - 2.0f * __builtin_amdgcn_rcpf(e + 1.0f);
}

__device__ __forceinline__ float readlane_f(float v, int l) {
    return __int_as_float(__builtin_amdgcn_readlane(__float_as_int(v), l));
}

__global__ __launch_bounds__(64) __attribute__((amdgpu_waves_per_eu(1, 1)))
void node_scan(const float* __restrict__ U,
               const float* __restrict__ W1, const float* __restrict__ b1,
               const float* __restrict__ W2, const float* __restrict__ b2,
               const float* __restrict__ W3, const float* __restrict__ b3,
               const float* __restrict__ wd, const float* __restrict__ bd,
               const float* __restrict__ wt, const float* __restrict__ bt,
               const float* __restrict__ wc, const float* __restrict__ bc,
               const float* __restrict__ h0,
               float* __restrict__ out)
{
    const int lane = threadIdx.x;            // 0..63
    const float dt = (float)(5.0 / 60.0);

    __shared__ __align__(16) float zbuf[64];          // z1 broadcast
    __shared__ __align__(16) float ubuf[2 * 64 * 8];  // u chunks, rows padded to 8
    __shared__ __align__(16) float zhist[64 * ZSTR];  // z2 history + broadcast
    __shared__ __align__(16) float cbuf[3 * 64];      // readout functionals

    // ---------------- weight preload (registers) ----------------
    float w1h[16];
#pragma unroll
    for (int j = 0; j < 16; ++j) w1h[j] = W1[lane * 23 + j];
    v2f W1up[3];
#pragma unroll
    for (int j = 0; j < 3; ++j) {
        W1up[j].x = W1[lane * 23 + 16 + 2 * j];
        W1up[j].y = W1[lane * 23 + 17 + 2 * j];
    }
    const float W1u6 = W1[lane * 23 + 22];
    const float b1r = b1[lane];

    v2f W2r[32];
#pragma unroll
    for (int j = 0; j < 32; ++j) {
        W2r[j].x = W2[lane * 64 + 2 * j];
        W2r[j].y = W2[lane * 64 + 2 * j + 1];
    }
    const float b2r = b2[lane];

    // ---------------- M = W1h @ W3 (row `lane`, fp32, one-time) ------------
    v2f Mr[32];
#pragma unroll
    for (int j = 0; j < 32; ++j) Mr[j] = (v2f){0.f, 0.f};
    for (int k = 0; k < 16; ++k) {
        const float w = w1h[k];
        const float* w3r = W3 + k * 64;
#pragma unroll
        for (int j = 0; j < 32; ++j) {
            v2f w3v = *(const v2f*)&w3r[2 * j];
            Mr[j] = __builtin_elementwise_fma((v2f){w, w}, w3v, Mr[j]);
        }
    }
    float m3od = 0.f;                        // W1h . b3 (seeds the M-dot)
    for (int k = 0; k < 16; ++k) m3od = fmaf(w1h[k], b3[k], m3od);

    // ---------------- readout functionals c = W3^T w → LDS -----------------
    {
        float cd = 0.f, ct = 0.f, cc = 0.f;
        for (int k = 0; k < 16; ++k) {
            const float w3v = W3[k * 64 + lane];
            cd = fmaf(wd[k], w3v, cd);
            ct = fmaf(wt[k], w3v, ct);
            cc = fmaf(wc[k], w3v, cc);
        }
        cbuf[lane] = cd; cbuf[64 + lane] = ct; cbuf[128 + lane] = cc;
    }
    float rbD = 0.f, rbT = 0.f, rbC = 0.f;          // dt*(w.b3)
    float rchD = bd[0], rchT = bt[0], rchC = bc[0]; // r at chunk start
    for (int k = 0; k < 16; ++k) {
        rbD = fmaf(wd[k], b3[k], rbD);  rchD = fmaf(wd[k], h0[k], rchD);
        rbT = fmaf(wt[k], b3[k], rbT);  rchT = fmaf(wt[k], h0[k], rchT);
        rbC = fmaf(wc[k], b3[k], rbC);  rchC = fmaf(wc[k], h0[k], rchC);
    }
    rbD *= dt; rbT *= dt; rbC *= dt;

    // ---------------- state ----------------
    float A = 0.f;                           // W1h-row-lane . h(t)
    for (int k = 0; k < 16; ++k) A = fmaf(w1h[k], h0[k], A);
    float zacc = 0.f;

    // ---------------- first u chunk + pad zero ----------------
#pragma unroll
    for (int r = 0; r < UDIM; ++r) {
        int flat = r * 64 + lane;
        int s = flat / 7, c = flat % 7;
        ubuf[s * 8 + c] = U[flat];
    }
    ubuf[lane * 8 + 7] = 0.f;
    ubuf[512 + lane * 8 + 7] = 0.f;
    __syncthreads();

    float tmp[UDIM];
#pragma unroll
    for (int r = 0; r < UDIM; ++r) tmp[r] = U[448 + r * 64 + lane];

    float uacc;
    {
        float4 ua = *(const float4*)&ubuf[0];
        float4 ub = *(const float4*)&ubuf[4];
        v2f v0 = __builtin_elementwise_fma(W1up[0], (v2f){ua.x, ua.y}, (v2f){0.f, 0.f});
        v0 = __builtin_elementwise_fma(W1up[1], (v2f){ua.z, ua.w}, v0);
        v0 = __builtin_elementwise_fma(W1up[2], (v2f){ub.x, ub.y}, v0);
        uacc = v0.x + v0.y + fmaf(W1u6, ub.z, b1r);
    }

    // ---------------- one Euler step -------------------------------------
    // uoff = LDS float-offset of NEXT step's u row (precomputed by caller)
    auto step = [&](int li, int uoff) {
        // ---- z1 = tanh(A + uacc) ----
        const float z1 = tanh_fast(A + uacc);
        zbuf[lane] = z1;
        float4 zz[16];
#pragma unroll
        for (int q = 0; q < 16; ++q) zz[q] = *(const float4*)&zbuf[q * 4];

        // next step's u (independent; issued early)
        float4 una = *(const float4*)&ubuf[uoff];
        float4 unb = *(const float4*)&ubuf[uoff + 4];

        // ---- z2 = tanh(W2 @ z1 + b2) ----
        v2f c0 = {b2r, 0.f}, c1 = {0.f, 0.f}, c2 = {0.f, 0.f}, c3 = {0.f, 0.f};
#pragma unroll
        for (int q = 0; q < 8; ++q) {
            c0 = __builtin_elementwise_fma(W2r[q * 4 + 0], (v2f){zz[2 * q].x, zz[2 * q].y}, c0);
            c1 = __builtin_elementwise_fma(W2r[q * 4 + 1], (v2f){zz[2 * q].z, zz[2 * q].w}, c1);
            c2 = __builtin_elementwise_fma(W2r[q * 4 + 2], (v2f){zz[2 * q + 1].x, zz[2 * q + 1].y}, c2);
            c3 = __builtin_elementwise_fma(W2r[q * 4 + 3], (v2f){zz[2 * q + 1].z, zz[2 * q + 1].w}, c3);
        }
        v2f cs = (c0 + c1) + (c2 + c3);
        const float z2 = tanh_fast(cs.x + cs.y);
        zhist[li * ZSTR + lane] = z2;      // history append = broadcast medium
        float4 qq[16];
        const float* zrow = &zhist[li * ZSTR];
#pragma unroll
        for (int q = 0; q < 16; ++q) qq[q] = *(const float4*)&zrow[q * 4];
        zacc += z2;

        // ---- A' = A + dt*(M @ z2 + W1h.b3)  (seeded accumulator) ----
        v2f m0 = {m3od, 0.f}, m1 = {0.f, 0.f}, m2 = {0.f, 0.f}, m3 = {0.f, 0.f};
#pragma unroll
        for (int q = 0; q < 8; ++q) {
            m0 = __builtin_elementwise_fma(Mr[q * 4 + 0], (v2f){qq[2 * q].x, qq[2 * q].y}, m0);
            m1 = __builtin_elementwise_fma(Mr[q * 4 + 1], (v2f){qq[2 * q].z, qq[2 * q].w}, m1);
            m2 = __builtin_elementwise_fma(Mr[q * 4 + 2], (v2f){qq[2 * q + 1].x, qq[2 * q + 1].y}, m2);
            m3 = __builtin_elementwise_fma(Mr[q * 4 + 3], (v2f){qq[2 * q + 1].z, qq[2 * q + 1].w}, m3);
        }
        v2f ms = (m0 + m1) + (m2 + m3);
        A = fmaf(dt, ms.x + ms.y, A);

        // ---- next step's uacc ----
        v2f uv = __builtin_elementwise_fma(W1up[0], (v2f){una.x, una.y}, (v2f){0.f, 0.f});
        uv = __builtin_elementwise_fma(W1up[1], (v2f){una.z, una.w}, uv);
        uv = __builtin_elementwise_fma(W1up[2], (v2f){unb.x, unb.y}, uv);
        uacc = uv.x + uv.y + fmaf(W1u6, unb.z, b1r);
    };

    // ---------------- batched readouts for one chunk (lane i ↔ step t0+i) --
    auto batch = [&](int t0) {
        const float* zr = &zhist[lane * ZSTR];
        v2f sd = {0.f, 0.f}, st = {0.f, 0.f}, sc = {0.f, 0.f};
#pragma unroll
        for (int q = 0; q < 32; ++q) {
            v2f zv = *(const v2f*)&zr[2 * q];
            sd = __builtin_elementwise_fma(*(const v2f*)&cbuf[2 * q],       zv, sd);
            st = __builtin_elementwise_fma(*(const v2f*)&cbuf[64 + 2 * q],  zv, st);
            sc = __builtin_elementwise_fma(*(const v2f*)&cbuf[128 + 2 * q], zv, sc);
        }
        float Sd = sd.x + sd.y, St = st.x + st.y, Sc = sc.x + sc.y;
        const float oD = Sd, oT = St, oC = Sc;
        // inclusive prefix scan over lanes (Hillis-Steele)
#pragma unroll
        for (int dl = 1; dl < 64; dl <<= 1) {
            float ud = __shfl_up(Sd, dl, 64);
            float ut = __shfl_up(St, dl, 64);
            float uc = __shfl_up(Sc, dl, 64);
            if (lane >= dl) { Sd += ud; St += ut; Sc += uc; }
        }
        const int t = t0 + lane;
        if (t < T_STEPS) {
            const float fl = (float)lane;
            out[t]               = fmaf(dt, Sd - oD, rchD) + fl * rbD;
            out[T_STEPS + t]     = fmaf(dt, St - oT, rchT) + fl * rbT;
            out[2 * T_STEPS + t] = fmaf(dt, Sc - oC, rchC) + fl * rbC;
        }
        rchD = fmaf(dt, readlane_f(Sd, 63), rchD) + 64.f * rbD;
        rchT = fmaf(dt, readlane_f(St, 63), rchT) + 64.f * rbT;
        rchC = fmaf(dt, readlane_f(Sc, 63), rchC) + 64.f * rbC;
    };

    // ---------------- chunked scan ----------------
    for (int cb = 0; cb < NCHUNK; ++cb) {
        const int buf512  = 512 * (cb & 1);
        const int other   = 512 * ((cb + 1) & 1);
        // commit tmp (chunk cb+1) BEFORE stepping (li=63's next-u needs it)
#pragma unroll
        for (int r = 0; r < UDIM; ++r) {
            int flat = r * 64 + lane;
            int s = flat / 7, c = flat % 7;
            ubuf[other + s * 8 + c] = tmp[r];
        }
        // issue global loads for chunk cb+2 (clamped)
        const int base = (cb + 2) * 448;
#pragma unroll
        for (int r = 0; r < UDIM; ++r) {
            int idx = base + r * 64 + lane;
            if (idx > T_STEPS * UDIM - 1) idx = T_STEPS * UDIM - 1;
            tmp[r] = U[idx];
        }
#pragma unroll 8
        for (int li = 0; li < 64; ++li) {
            const int uoff = (li < 63) ? buf512 + (li + 1) * 8 : other;
            step(li, uoff);
        }
        batch(cb * 64);
    }
    for (int li = 0; li < TAIL; ++li) step(li, (li + 1) * 8);
    batch(NCHUNK * 64);   // masked by t < T_STEPS

    // ---------------- final state: h(T) = h0 + dt*W3@zacc + T*dt*b3 --------
    zbuf[lane] = zacc;
    float4 za[16];
#pragma unroll
    for (int q = 0; q < 16; ++q) za[q] = *(const float4*)&zbuf[q * 4];
    const int row = lane & 15;
    const float* w3r = W3 + row * 64;
    float h0a = 0.f, h1a = 0.f;
#pragma unroll
    for (int q = 0; q < 16; ++q) {
        h0a = fmaf(w3r[4 * q + 0], za[q].x, h0a);
        h1a = fmaf(w3r[4 * q + 1], za[q].y, h1a);
        h0a = fmaf(w3r[4 * q + 2], za[q].z, h0a);
        h1a = fmaf(w3r[4 * q + 3], za[q].w, h1a);
    }
    const float hT = h0[row] + dt * (h0a + h1a) + (float)T_STEPS * dt * b3[row];
    if (lane < 16) out[3 * T_STEPS + lane] = hT;
}

extern "C" void kernel_launch(void* const* d_in, const int* in_sizes, int n_in,
                              void* d_out, int out_size, void* d_ws, size_t ws_size,
                              hipStream_t stream) {
    const float* U  = (const float*)d_in[0];
    const float* W1 = (const float*)d_in[1];
    const float* b1 = (const float*)d_in[2];
    const float* W2 = (const float*)d_in[3];
    const float* b2 = (const float*)d_in[4];
    const float* W3 = (const float*)d_in[5];
    const float* b3 = (const float*)d_in[6];
    const float* wd = (const float*)d_in[7];
    const float* bd = (const float*)d_in[8];
    const float* wt = (const float*)d_in[9];
    const float* bt = (const float*)d_in[10];
    const float* wc = (const float*)d_in[11];
    const float* bc = (const float*)d_in[12];
    const float* h0 = (const float*)d_in[13];
    (void)in_sizes; (void)n_in; (void)out_size; (void)d_ws; (void)ws_size;

    node_scan<<<dim3(1), dim3(64), 0, stream>>>(U, W1, b1, W2, b2, W3, b3,
                                                wd, bd, wt, bt, wc, bc, h0,
                                                (float*)d_out);
}

// Round 11
// 28547.293 us; speedup vs baseline: 1.8043x; 1.2367x over previous
//
#include <hip/hip_runtime.h>

typedef float v2f __attribute__((ext_vector_type(2)));

#define T_STEPS 100000
#define UDIM 7
#define NCHUNK 1562   /* full 64-step chunks */
#define TAIL 32       /* 100000 - 1562*64 */
#define ZSTR 68       /* zhist row stride (floats): 16B-aligned rows */

__device__ __forceinline__ float tanh_fast(float x) {
    float e = __expf(2.0f * x);
    return 1.0f - 2.0f * __builtin_amdgcn_rcpf(e + 1.0f);
}

__device__ __forceinline__ float readlane_f(float v, int l) {
    return __int_as_float(__builtin_amdgcn_readlane(__float_as_int(v), l));
}

// value of v from lane (self ^ {1,2,3}) within each quad — pure VALU
template <int CTRL>
__device__ __forceinline__ float dpp_f(float v) {
    return __int_as_float(__builtin_amdgcn_update_dpp(
        0, __float_as_int(v), CTRL, 0xF, 0xF, true));
}

__global__ __launch_bounds__(64) __attribute__((amdgpu_waves_per_eu(1, 1)))
void node_scan(const float* __restrict__ U,
               const float* __restrict__ W1, const float* __restrict__ b1,
               const float* __restrict__ W2, const float* __restrict__ b2,
               const float* __restrict__ W3, const float* __restrict__ b3,
               const float* __restrict__ wd, const float* __restrict__ bd,
               const float* __restrict__ wt, const float* __restrict__ bt,
               const float* __restrict__ wc, const float* __restrict__ bc,
               const float* __restrict__ h0,
               float* __restrict__ out)
{
    const int lane = threadIdx.x;            // 0..63 = 4*g + q
    const int g = lane >> 2;                 // output group (0..15)
    const int q = lane & 3;                  // z-segment this lane reads (0..3)
    const float dt = (float)(5.0 / 60.0);

    __shared__ __align__(16) float zbuf[64];          // z1 broadcast
    __shared__ __align__(16) float ubuf[2 * 64 * 8];  // u chunks, rows padded to 8
    __shared__ __align__(16) float zhist[64 * ZSTR];  // z2 history + broadcast
    __shared__ __align__(16) float cbuf[3 * 64];      // readout functionals
    __shared__ __align__(16) float Msh[64 * 64];      // M staging (init only)

    // ---------------- weight preload (registers) ----------------
    float w1h[16];
#pragma unroll
    for (int j = 0; j < 16; ++j) w1h[j] = W1[lane * 23 + j];
    v2f W1up[3];
#pragma unroll
    for (int j = 0; j < 3; ++j) {
        W1up[j].x = W1[lane * 23 + 16 + 2 * j];
        W1up[j].y = W1[lane * 23 + 17 + 2 * j];
    }
    const float W1u6 = W1[lane * 23 + 22];
    const float b1r = b1[lane];
    const float b2r = b2[lane];

    // ---- W2 quarter-slices: rows 4g+(q^d), cols [16q,16q+16) ----
    v2f W2p[4][8];
#pragma unroll
    for (int d = 0; d < 4; ++d) {
        const int orow = (g << 2) | (q ^ d);
        const float* w2r = W2 + orow * 64 + q * 16;
#pragma unroll
        for (int j = 0; j < 8; ++j) W2p[d][j] = (v2f){ w2r[2 * j], w2r[2 * j + 1] };
    }

    // ---------------- M = W1h @ W3, staged via LDS ----------------
    for (int c = 0; c < 64; ++c) {
        float acc = 0.f;
#pragma unroll
        for (int k = 0; k < 16; ++k) acc = fmaf(w1h[k], W3[k * 64 + c], acc);
        Msh[lane * 64 + c] = acc;
    }
    __syncthreads();
    v2f Mp[4][8];
#pragma unroll
    for (int d = 0; d < 4; ++d) {
        const int orow = (g << 2) | (q ^ d);
        const float* mr = Msh + orow * 64 + q * 16;
#pragma unroll
        for (int j = 0; j < 8; ++j) Mp[d][j] = (v2f){ mr[2 * j], mr[2 * j + 1] };
    }
    float m3od = 0.f;                        // W1h(row lane) . b3 — seeds d=0
#pragma unroll
    for (int k = 0; k < 16; ++k) m3od = fmaf(w1h[k], b3[k], m3od);

    // ---------------- readout functionals c = W3^T w → LDS -----------------
    {
        float cd = 0.f, ct = 0.f, cc = 0.f;
        for (int k = 0; k < 16; ++k) {
            const float w3v = W3[k * 64 + lane];
            cd = fmaf(wd[k], w3v, cd);
            ct = fmaf(wt[k], w3v, ct);
            cc = fmaf(wc[k], w3v, cc);
        }
        cbuf[lane] = cd; cbuf[64 + lane] = ct; cbuf[128 + lane] = cc;
    }
    float rbD = 0.f, rbT = 0.f, rbC = 0.f;          // dt*(w.b3)
    float rchD = bd[0], rchT = bt[0], rchC = bc[0]; // r at chunk start
    for (int k = 0; k < 16; ++k) {
        rbD = fmaf(wd[k], b3[k], rbD);  rchD = fmaf(wd[k], h0[k], rchD);
        rbT = fmaf(wt[k], b3[k], rbT);  rchT = fmaf(wt[k], h0[k], rchT);
        rbC = fmaf(wc[k], b3[k], rbC);  rchC = fmaf(wc[k], h0[k], rchC);
    }
    rbD *= dt; rbT *= dt; rbC *= dt;

    // ---------------- state ----------------
    float A = 0.f;                           // W1h(row lane) . h(t)
    for (int k = 0; k < 16; ++k) A = fmaf(w1h[k], h0[k], A);
    float zacc = 0.f;

    // ---------------- first u chunk + pad zero ----------------
#pragma unroll
    for (int r = 0; r < UDIM; ++r) {
        int flat = r * 64 + lane;
        int s = flat / 7, c = flat % 7;
        ubuf[s * 8 + c] = U[flat];
    }
    ubuf[lane * 8 + 7] = 0.f;
    ubuf[512 + lane * 8 + 7] = 0.f;
    __syncthreads();

    float tmp[UDIM];
#pragma unroll
    for (int r = 0; r < UDIM; ++r) tmp[r] = U[448 + r * 64 + lane];

    float uacc;
    {
        float4 ua = *(const float4*)&ubuf[0];
        float4 ub = *(const float4*)&ubuf[4];
        v2f v0 = __builtin_elementwise_fma(W1up[0], (v2f){ua.x, ua.y}, (v2f){0.f, 0.f});
        v0 = __builtin_elementwise_fma(W1up[1], (v2f){ua.z, ua.w}, v0);
        v0 = __builtin_elementwise_fma(W1up[2], (v2f){ub.x, ub.y}, v0);
        uacc = v0.x + v0.y + fmaf(W1u6, ub.z, b1r);
    }

    // ---------------- one Euler step -------------------------------------
    auto step = [&](int li, int uoff) {
        // ---- z1 = tanh(A + uacc) ----
        const float z1 = tanh_fast(A + uacc);
        zbuf[lane] = z1;
        // segment gather: 4 x b128 (16 floats of segment q)
        float4 s0 = *(const float4*)&zbuf[q * 16 + 0];
        float4 s1 = *(const float4*)&zbuf[q * 16 + 4];
        float4 s2 = *(const float4*)&zbuf[q * 16 + 8];
        float4 s3 = *(const float4*)&zbuf[q * 16 + 12];

        // next step's u (independent; issued early)
        float4 una = *(const float4*)&ubuf[uoff];
        float4 unb = *(const float4*)&ubuf[uoff + 4];

        // ---- W2 quarter-dots for outputs 4g+(q^d) ----
        v2f e0 = {s0.x, s0.y}, e1 = {s0.z, s0.w};
        v2f e2 = {s1.x, s1.y}, e3 = {s1.z, s1.w};
        v2f e4 = {s2.x, s2.y}, e5 = {s2.z, s2.w};
        v2f e6 = {s3.x, s3.y}, e7 = {s3.z, s3.w};
        v2f c0 = {b2r, 0.f}, c1 = {0.f, 0.f}, c2 = {0.f, 0.f}, c3 = {0.f, 0.f};
        c0 = __builtin_elementwise_fma(W2p[0][0], e0, c0);
        c1 = __builtin_elementwise_fma(W2p[1][0], e0, c1);
        c2 = __builtin_elementwise_fma(W2p[2][0], e0, c2);
        c3 = __builtin_elementwise_fma(W2p[3][0], e0, c3);
        c0 = __builtin_elementwise_fma(W2p[0][1], e1, c0);
        c1 = __builtin_elementwise_fma(W2p[1][1], e1, c1);
        c2 = __builtin_elementwise_fma(W2p[2][1], e1, c2);
        c3 = __builtin_elementwise_fma(W2p[3][1], e1, c3);
        c0 = __builtin_elementwise_fma(W2p[0][2], e2, c0);
        c1 = __builtin_elementwise_fma(W2p[1][2], e2, c1);
        c2 = __builtin_elementwise_fma(W2p[2][2], e2, c2);
        c3 = __builtin_elementwise_fma(W2p[3][2], e2, c3);
        c0 = __builtin_elementwise_fma(W2p[0][3], e3, c0);
        c1 = __builtin_elementwise_fma(W2p[1][3], e3, c1);
        c2 = __builtin_elementwise_fma(W2p[2][3], e3, c2);
        c3 = __builtin_elementwise_fma(W2p[3][3], e3, c3);
        c0 = __builtin_elementwise_fma(W2p[0][4], e4, c0);
        c1 = __builtin_elementwise_fma(W2p[1][4], e4, c1);
        c2 = __builtin_elementwise_fma(W2p[2][4], e4, c2);
        c3 = __builtin_elementwise_fma(W2p[3][4], e4, c3);
        c0 = __builtin_elementwise_fma(W2p[0][5], e5, c0);
        c1 = __builtin_elementwise_fma(W2p[1][5], e5, c1);
        c2 = __builtin_elementwise_fma(W2p[2][5], e5, c2);
        c3 = __builtin_elementwise_fma(W2p[3][5], e5, c3);
        c0 = __builtin_elementwise_fma(W2p[0][6], e6, c0);
        c1 = __builtin_elementwise_fma(W2p[1][6], e6, c1);
        c2 = __builtin_elementwise_fma(W2p[2][6], e6, c2);
        c3 = __builtin_elementwise_fma(W2p[3][6], e6, c3);
        c0 = __builtin_elementwise_fma(W2p[0][7], e7, c0);
        c1 = __builtin_elementwise_fma(W2p[1][7], e7, c1);
        c2 = __builtin_elementwise_fma(W2p[2][7], e7, c2);
        c3 = __builtin_elementwise_fma(W2p[3][7], e7, c3);
        const float P0 = c0.x + c0.y;
        const float P1 = c1.x + c1.y;
        const float P2 = c2.x + c2.y;
        const float P3 = c3.x + c3.y;
        // quad xor-reduce, all VALU: out[lane] lands on lane
        const float Q = P0 + dpp_f<0xB1>(P1) + dpp_f<0x4E>(P2) + dpp_f<0x1B>(P3);
        const float z2 = tanh_fast(Q);
        zhist[li * ZSTR + lane] = z2;      // history append = broadcast medium
        const float* zrow = &zhist[li * ZSTR + q * 16];
        float4 t0 = *(const float4*)&zrow[0];
        float4 t1 = *(const float4*)&zrow[4];
        float4 t2 = *(const float4*)&zrow[8];
        float4 t3 = *(const float4*)&zrow[12];
        zacc += z2;

        // ---- M quarter-dots → A' = A + dt*(M@z2 + W1h.b3) ----
        v2f f0 = {t0.x, t0.y}, f1 = {t0.z, t0.w};
        v2f f2 = {t1.x, t1.y}, f3 = {t1.z, t1.w};
        v2f f4 = {t2.x, t2.y}, f5 = {t2.z, t2.w};
        v2f f6 = {t3.x, t3.y}, f7 = {t3.z, t3.w};
        v2f m0 = {m3od, 0.f}, m1 = {0.f, 0.f}, m2 = {0.f, 0.f}, m3 = {0.f, 0.f};
        m0 = __builtin_elementwise_fma(Mp[0][0], f0, m0);
        m1 = __builtin_elementwise_fma(Mp[1][0], f0, m1);
        m2 = __builtin_elementwise_fma(Mp[2][0], f0, m2);
        m3 = __builtin_elementwise_fma(Mp[3][0], f0, m3);
        m0 = __builtin_elementwise_fma(Mp[0][1], f1, m0);
        m1 = __builtin_elementwise_fma(Mp[1][1], f1, m1);
        m2 = __builtin_elementwise_fma(Mp[2][1], f1, m2);
        m3 = __builtin_elementwise_fma(Mp[3][1], f1, m3);
        m0 = __builtin_elementwise_fma(Mp[0][2], f2, m0);
        m1 = __builtin_elementwise_fma(Mp[1][2], f2, m1);
        m2 = __builtin_elementwise_fma(Mp[2][2], f2, m2);
        m3 = __builtin_elementwise_fma(Mp[3][2], f2, m3);
        m0 = __builtin_elementwise_fma(Mp[0][3], f3, m0);
        m1 = __builtin_elementwise_fma(Mp[1][3], f3, m1);
        m2 = __builtin_elementwise_fma(Mp[2][3], f3, m2);
        m3 = __builtin_elementwise_fma(Mp[3][3], f3, m3);
        m0 = __builtin_elementwise_fma(Mp[0][4], f4, m0);
        m1 = __builtin_elementwise_fma(Mp[1][4], f4, m1);
        m2 = __builtin_elementwise_fma(Mp[2][4], f4, m2);
        m3 = __builtin_elementwise_fma(Mp[3][4], f4, m3);
        m0 = __builtin_elementwise_fma(Mp[0][5], f5, m0);
        m1 = __builtin_elementwise_fma(Mp[1][5], f5, m1);
        m2 = __builtin_elementwise_fma(Mp[2][5], f5, m2);
        m3 = __builtin_elementwise_fma(Mp[3][5], f5, m3);
        m0 = __builtin_elementwise_fma(Mp[0][6], f6, m0);
        m1 = __builtin_elementwise_fma(Mp[1][6], f6, m1);
        m2 = __builtin_elementwise_fma(Mp[2][6], f6, m2);
        m3 = __builtin_elementwise_fma(Mp[3][6], f6, m3);
        m0 = __builtin_elementwise_fma(Mp[0][7], f7, m0);
        m1 = __builtin_elementwise_fma(Mp[1][7], f7, m1);
        m2 = __builtin_elementwise_fma(Mp[2][7], f7, m2);
        m3 = __builtin_elementwise_fma(Mp[3][7], f7, m3);
        const float R0 = m0.x + m0.y;
        const float R1 = m1.x + m1.y;
        const float R2 = m2.x + m2.y;
        const float R3 = m3.x + m3.y;
        const float R = R0 + dpp_f<0xB1>(R1) + dpp_f<0x4E>(R2) + dpp_f<0x1B>(R3);
        A = fmaf(dt, R, A);

        // ---- next step's uacc ----
        v2f uv = __builtin_elementwise_fma(W1up[0], (v2f){una.x, una.y}, (v2f){0.f, 0.f});
        uv = __builtin_elementwise_fma(W1up[1], (v2f){una.z, una.w}, uv);
        uv = __builtin_elementwise_fma(W1up[2], (v2f){unb.x, unb.y}, uv);
        uacc = uv.x + uv.y + fmaf(W1u6, unb.z, b1r);
    };

    // ---------------- batched readouts for one chunk (lane i ↔ step t0+i) --
    auto batch = [&](int t0) {
        const float* zr = &zhist[lane * ZSTR];
        v2f sd = {0.f, 0.f}, st = {0.f, 0.f}, sc = {0.f, 0.f};
#pragma unroll
        for (int qq = 0; qq < 32; ++qq) {
            v2f zv = *(const v2f*)&zr[2 * qq];
            sd = __builtin_elementwise_fma(*(const v2f*)&cbuf[2 * qq],       zv, sd);
            st = __builtin_elementwise_fma(*(const v2f*)&cbuf[64 + 2 * qq],  zv, st);
            sc = __builtin_elementwise_fma(*(const v2f*)&cbuf[128 + 2 * qq], zv, sc);
        }
        float Sd = sd.x + sd.y, St = st.x + st.y, Sc = sc.x + sc.y;
        const float oD = Sd, oT = St, oC = Sc;
        // inclusive prefix scan over lanes (Hillis-Steele)
#pragma unroll
        for (int dl = 1; dl < 64; dl <<= 1) {
            float ud = __shfl_up(Sd, dl, 64);
            float ut = __shfl_up(St, dl, 64);
            float uc = __shfl_up(Sc, dl, 64);
            if (lane >= dl) { Sd += ud; St += ut; Sc += uc; }
        }
        const int t = t0 + lane;
        if (t < T_STEPS) {
            const float fl = (float)lane;
            out[t]               = fmaf(dt, Sd - oD, rchD) + fl * rbD;
            out[T_STEPS + t]     = fmaf(dt, St - oT, rchT) + fl * rbT;
            out[2 * T_STEPS + t] = fmaf(dt, Sc - oC, rchC) + fl * rbC;
        }
        rchD = fmaf(dt, readlane_f(Sd, 63), rchD) + 64.f * rbD;
        rchT = fmaf(dt, readlane_f(St, 63), rchT) + 64.f * rbT;
        rchC = fmaf(dt, readlane_f(Sc, 63), rchC) + 64.f * rbC;
    };

    // ---------------- chunked scan ----------------
    for (int cb = 0; cb < NCHUNK; ++cb) {
        const int buf512  = 512 * (cb & 1);
        const int other   = 512 * ((cb + 1) & 1);
#pragma unroll
        for (int r = 0; r < UDIM; ++r) {
            int flat = r * 64 + lane;
            int s = flat / 7, c = flat % 7;
            ubuf[other + s * 8 + c] = tmp[r];
        }
        const int base = (cb + 2) * 448;
#pragma unroll
        for (int r = 0; r < UDIM; ++r) {
            int idx = base + r * 64 + lane;
            if (idx > T_STEPS * UDIM - 1) idx = T_STEPS * UDIM - 1;
            tmp[r] = U[idx];
        }
#pragma unroll 8
        for (int li = 0; li < 64; ++li) {
            const int uoff = (li < 63) ? buf512 + (li + 1) * 8 : other;
            step(li, uoff);
        }
        batch(cb * 64);
    }
    for (int li = 0; li < TAIL; ++li) step(li, (li + 1) * 8);
    batch(NCHUNK * 64);   // masked by t < T_STEPS

    // ---------------- final state: h(T) = h0 + dt*W3@zacc + T*dt*b3 --------
    zbuf[lane] = zacc;
    float4 za[16];
#pragma unroll
    for (int qq = 0; qq < 16; ++qq) za[qq] = *(const float4*)&zbuf[qq * 4];
    const int row = lane & 15;
    const float* w3r = W3 + row * 64;
    float h0a = 0.f, h1a = 0.f;
#pragma unroll
    for (int qq = 0; qq < 16; ++qq) {
        h0a = fmaf(w3r[4 * qq + 0], za[qq].x, h0a);
        h1a = fmaf(w3r[4 * qq + 1], za[qq].y, h1a);
        h0a = fmaf(w3r[4 * qq + 2], za[qq].z, h0a);
        h1a = fmaf(w3r[4 * qq + 3], za[qq].w, h1a);
    }
    const float hT = h0[row] + dt * (h0a + h1a) + (float)T_STEPS * dt * b3[row];
    if (lane < 16) out[3 * T_STEPS + lane] = hT;
}

extern "C" void kernel_launch(void* const* d_in, const int* in_sizes, int n_in,
                              void* d_out, int out_size, void* d_ws, size_t ws_size,
                              hipStream_t stream) {
    const float* U  = (const float*)d_in[0];
    const float* W1 = (const float*)d_in[1];
    const float* b1 = (const float*)d_in[2];
    const float* W2 = (const float*)d_in[3];
    const float* b2 = (const float*)d_in[4];
    const float* W3 = (const float*)d_in[5];
    const float* b3 = (const float*)d_in[6];
    const float* wd = (const float*)d_in[7];
    const float* bd = (const float*)d_in[8];
    const float* wt = (const float*)d_in[9];
    const float* bt = (const float*)d_in[10];
    const float* wc = (const float*)d_in[11];
    const float* bc = (const float*)d_in[12];
    const float* h0 = (const float*)d_in[13];
    (void)in_sizes; (void)n_in; (void)out_size; (void)d_ws; (void)ws_size;

    node_scan<<<dim3(1), dim3(64), 0, stream>>>(U, W1, b1, W2, b2, W3, b3,
                                                wd, bd, wt, bt, wc, bc, h0,
                                                (float*)d_out);
}

// Round 12
// 27808.405 us; speedup vs baseline: 1.8522x; 1.0266x over previous
//
#include <hip/hip_runtime.h>

typedef float v2f __attribute__((ext_vector_type(2)));

#define T_STEPS 100000
#define UDIM 7
#define NCHUNK 1562   /* full 64-step chunks */
#define TAIL 32       /* 100000 - 1562*64 */
#define ZSTR 68       /* zhist row stride (floats) */
#define ZH (64 * ZSTR)

__device__ __forceinline__ float tanh_fast(float x) {
    float e = __expf(2.0f * x);
    return 1.0f - 2.0f * __builtin_amdgcn_rcpf(e + 1.0f);
}

__device__ __forceinline__ float readlane_f(float v, int l) {
    return __int_as_float(__builtin_amdgcn_readlane(__float_as_int(v), l));
}

template <int CTRL>
__device__ __forceinline__ float dpp_f(float v) {
    return __int_as_float(__builtin_amdgcn_update_dpp(
        0, __float_as_int(v), CTRL, 0xF, 0xF, true));
}

__global__ __launch_bounds__(128) __attribute__((amdgpu_waves_per_eu(1, 1)))
void node_scan(const float* __restrict__ U,
               const float* __restrict__ W1, const float* __restrict__ b1,
               const float* __restrict__ W2, const float* __restrict__ b2,
               const float* __restrict__ W3, const float* __restrict__ b3,
               const float* __restrict__ wd, const float* __restrict__ bd,
               const float* __restrict__ wt, const float* __restrict__ bt,
               const float* __restrict__ wc, const float* __restrict__ bc,
               const float* __restrict__ h0,
               float* __restrict__ out)
{
    const int tid  = threadIdx.x;
    const int wv   = tid >> 6;               // 0 = compute wave, 1 = service wave
    const int lane = tid & 63;
    const int g = lane >> 2;                 // output group (0..15)
    const int q = lane & 3;                  // z-segment this lane reads (0..3)
    const float dt = (float)(5.0 / 60.0);

    __shared__ __align__(16) float zbuf[64];          // z1 broadcast (wave0)
    __shared__ __align__(16) float ubuf[3 * 512];     // u chunks, triple-buffered
    __shared__ __align__(16) float zhist[2 * ZH];     // z2 history, double-buffered
    __shared__ __align__(16) float cbuf[3 * 64];      // readout functionals (wave1)
    __shared__ __align__(16) float Msh[64 * 64];      // M staging (init only)
    __shared__ int flg[4];                            // 0=done,1=staged,2=batched

    if (tid == 0) { flg[0] = 0; flg[1] = 3; flg[2] = 0; }

    // ================= per-wave init (before the single barrier) ===========
    // wave0 registers
    float w1h[16]; v2f W1up[3]; float W1u6 = 0.f, b1r = 0.f, b2r = 0.f;
    v2f W2p[4][8];
    // wave1 registers
    float rbD = 0.f, rbT = 0.f, rbC = 0.f, rchD = 0.f, rchT = 0.f, rchC = 0.f;

    if (wv == 0) {
#pragma unroll
        for (int j = 0; j < 16; ++j) w1h[j] = W1[lane * 23 + j];
#pragma unroll
        for (int j = 0; j < 3; ++j) {
            W1up[j].x = W1[lane * 23 + 16 + 2 * j];
            W1up[j].y = W1[lane * 23 + 17 + 2 * j];
        }
        W1u6 = W1[lane * 23 + 22];
        b1r = b1[lane];
        b2r = b2[lane];
#pragma unroll
        for (int d = 0; d < 4; ++d) {
            const int orow = (g << 2) | (q ^ d);
            const float* w2r = W2 + orow * 64 + q * 16;
#pragma unroll
            for (int j = 0; j < 8; ++j) W2p[d][j] = (v2f){ w2r[2 * j], w2r[2 * j + 1] };
        }
        // M = W1h @ W3 rows → LDS
        for (int c = 0; c < 64; ++c) {
            float acc = 0.f;
#pragma unroll
            for (int k = 0; k < 16; ++k) acc = fmaf(w1h[k], W3[k * 64 + c], acc);
            Msh[lane * 64 + c] = acc;
        }
    } else {
        // readout functionals c = W3^T w → LDS
        float cd = 0.f, ct = 0.f, cc = 0.f;
        for (int k = 0; k < 16; ++k) {
            const float w3v = W3[k * 64 + lane];
            cd = fmaf(wd[k], w3v, cd);
            ct = fmaf(wt[k], w3v, ct);
            cc = fmaf(wc[k], w3v, cc);
        }
        cbuf[lane] = cd; cbuf[64 + lane] = ct; cbuf[128 + lane] = cc;
        rchD = bd[0]; rchT = bt[0]; rchC = bc[0];
        for (int k = 0; k < 16; ++k) {
            rbD = fmaf(wd[k], b3[k], rbD);  rchD = fmaf(wd[k], h0[k], rchD);
            rbT = fmaf(wt[k], b3[k], rbT);  rchT = fmaf(wt[k], h0[k], rchT);
            rbC = fmaf(wc[k], b3[k], rbC);  rchC = fmaf(wc[k], h0[k], rchC);
        }
        rbD *= dt; rbT *= dt; rbC *= dt;
        // stage chunks 0,1,2 into buffers 0,1,2; zero pad column
#pragma unroll
        for (int c = 0; c < 3; ++c) {
            const int base = c * 448, dst = c * 512;
#pragma unroll
            for (int r = 0; r < UDIM; ++r) {
                int flat = r * 64 + lane;
                int s = flat / 7, cc2 = flat % 7;
                ubuf[dst + s * 8 + cc2] = U[base + flat];
            }
            ubuf[dst + lane * 8 + 7] = 0.f;
        }
    }
    __syncthreads();

    if (wv == 0) {
        // ---------- wave0 post-barrier init ----------
        v2f Mp[4][8];
#pragma unroll
        for (int d = 0; d < 4; ++d) {
            const int orow = (g << 2) | (q ^ d);
            const float* mr = Msh + orow * 64 + q * 16;
#pragma unroll
            for (int j = 0; j < 8; ++j) Mp[d][j] = (v2f){ mr[2 * j], mr[2 * j + 1] };
        }
        float m3od = 0.f;
#pragma unroll
        for (int k = 0; k < 16; ++k) m3od = fmaf(w1h[k], b3[k], m3od);
        float A = 0.f;
        for (int k = 0; k < 16; ++k) A = fmaf(w1h[k], h0[k], A);
        float zacc = 0.f;
        float uacc;
        {
            float4 ua = *(const float4*)&ubuf[0];
            float4 ub = *(const float4*)&ubuf[4];
            v2f v0 = __builtin_elementwise_fma(W1up[0], (v2f){ua.x, ua.y}, (v2f){0.f, 0.f});
            v0 = __builtin_elementwise_fma(W1up[1], (v2f){ua.z, ua.w}, v0);
            v0 = __builtin_elementwise_fma(W1up[2], (v2f){ub.x, ub.y}, v0);
            uacc = v0.x + v0.y + fmaf(W1u6, ub.z, b1r);
        }

        auto step = [&](int li, int uoff, int zbase) {
            const float z1 = tanh_fast(A + uacc);
            zbuf[lane] = z1;
            float4 s0 = *(const float4*)&zbuf[q * 16 + 0];
            float4 s1 = *(const float4*)&zbuf[q * 16 + 4];
            float4 s2 = *(const float4*)&zbuf[q * 16 + 8];
            float4 s3 = *(const float4*)&zbuf[q * 16 + 12];

            float4 una = *(const float4*)&ubuf[uoff];
            float4 unb = *(const float4*)&ubuf[uoff + 4];

            v2f e0 = {s0.x, s0.y}, e1 = {s0.z, s0.w};
            v2f e2 = {s1.x, s1.y}, e3 = {s1.z, s1.w};
            v2f e4 = {s2.x, s2.y}, e5 = {s2.z, s2.w};
            v2f e6 = {s3.x, s3.y}, e7 = {s3.z, s3.w};
            v2f c0 = {b2r, 0.f}, c1 = {0.f, 0.f}, c2 = {0.f, 0.f}, c3 = {0.f, 0.f};
            c0 = __builtin_elementwise_fma(W2p[0][0], e0, c0);
            c1 = __builtin_elementwise_fma(W2p[1][0], e0, c1);
            c2 = __builtin_elementwise_fma(W2p[2][0], e0, c2);
            c3 = __builtin_elementwise_fma(W2p[3][0], e0, c3);
            c0 = __builtin_elementwise_fma(W2p[0][1], e1, c0);
            c1 = __builtin_elementwise_fma(W2p[1][1], e1, c1);
            c2 = __builtin_elementwise_fma(W2p[2][1], e1, c2);
            c3 = __builtin_elementwise_fma(W2p[3][1], e1, c3);
            c0 = __builtin_elementwise_fma(W2p[0][2], e2, c0);
            c1 = __builtin_elementwise_fma(W2p[1][2], e2, c1);
            c2 = __builtin_elementwise_fma(W2p[2][2], e2, c2);
            c3 = __builtin_elementwise_fma(W2p[3][2], e2, c3);
            c0 = __builtin_elementwise_fma(W2p[0][3], e3, c0);
            c1 = __builtin_elementwise_fma(W2p[1][3], e3, c1);
            c2 = __builtin_elementwise_fma(W2p[2][3], e3, c2);
            c3 = __builtin_elementwise_fma(W2p[3][3], e3, c3);
            c0 = __builtin_elementwise_fma(W2p[0][4], e4, c0);
            c1 = __builtin_elementwise_fma(W2p[1][4], e4, c1);
            c2 = __builtin_elementwise_fma(W2p[2][4], e4, c2);
            c3 = __builtin_elementwise_fma(W2p[3][4], e4, c3);
            c0 = __builtin_elementwise_fma(W2p[0][5], e5, c0);
            c1 = __builtin_elementwise_fma(W2p[1][5], e5, c1);
            c2 = __builtin_elementwise_fma(W2p[2][5], e5, c2);
            c3 = __builtin_elementwise_fma(W2p[3][5], e5, c3);
            c0 = __builtin_elementwise_fma(W2p[0][6], e6, c0);
            c1 = __builtin_elementwise_fma(W2p[1][6], e6, c1);
            c2 = __builtin_elementwise_fma(W2p[2][6], e6, c2);
            c3 = __builtin_elementwise_fma(W2p[3][6], e6, c3);
            c0 = __builtin_elementwise_fma(W2p[0][7], e7, c0);
            c1 = __builtin_elementwise_fma(W2p[1][7], e7, c1);
            c2 = __builtin_elementwise_fma(W2p[2][7], e7, c2);
            c3 = __builtin_elementwise_fma(W2p[3][7], e7, c3);
            const float P0 = c0.x + c0.y;
            const float P1 = c1.x + c1.y;
            const float P2 = c2.x + c2.y;
            const float P3 = c3.x + c3.y;
            const float Q = P0 + dpp_f<0xB1>(P1) + dpp_f<0x4E>(P2) + dpp_f<0x1B>(P3);
            const float z2 = tanh_fast(Q);
            zhist[zbase + li * ZSTR + lane] = z2;
            const float* zrow = &zhist[zbase + li * ZSTR + q * 16];
            float4 t0 = *(const float4*)&zrow[0];
            float4 t1 = *(const float4*)&zrow[4];
            float4 t2 = *(const float4*)&zrow[8];
            float4 t3 = *(const float4*)&zrow[12];
            zacc += z2;

            v2f f0 = {t0.x, t0.y}, f1 = {t0.z, t0.w};
            v2f f2 = {t1.x, t1.y}, f3 = {t1.z, t1.w};
            v2f f4 = {t2.x, t2.y}, f5 = {t2.z, t2.w};
            v2f f6 = {t3.x, t3.y}, f7 = {t3.z, t3.w};
            v2f m0 = {m3od, 0.f}, m1 = {0.f, 0.f}, m2 = {0.f, 0.f}, m3 = {0.f, 0.f};
            m0 = __builtin_elementwise_fma(Mp[0][0], f0, m0);
            m1 = __builtin_elementwise_fma(Mp[1][0], f0, m1);
            m2 = __builtin_elementwise_fma(Mp[2][0], f0, m2);
            m3 = __builtin_elementwise_fma(Mp[3][0], f0, m3);
            m0 = __builtin_elementwise_fma(Mp[0][1], f1, m0);
            m1 = __builtin_elementwise_fma(Mp[1][1], f1, m1);
            m2 = __builtin_elementwise_fma(Mp[2][1], f1, m2);
            m3 = __builtin_elementwise_fma(Mp[3][1], f1, m3);
            m0 = __builtin_elementwise_fma(Mp[0][2], f2, m0);
            m1 = __builtin_elementwise_fma(Mp[1][2], f2, m1);
            m2 = __builtin_elementwise_fma(Mp[2][2], f2, m2);
            m3 = __builtin_elementwise_fma(Mp[3][2], f2, m3);
            m0 = __builtin_elementwise_fma(Mp[0][3], f3, m0);
            m1 = __builtin_elementwise_fma(Mp[1][3], f3, m1);
            m2 = __builtin_elementwise_fma(Mp[2][3], f3, m2);
            m3 = __builtin_elementwise_fma(Mp[3][3], f3, m3);
            m0 = __builtin_elementwise_fma(Mp[0][4], f4, m0);
            m1 = __builtin_elementwise_fma(Mp[1][4], f4, m1);
            m2 = __builtin_elementwise_fma(Mp[2][4], f4, m2);
            m3 = __builtin_elementwise_fma(Mp[3][4], f4, m3);
            m0 = __builtin_elementwise_fma(Mp[0][5], f5, m0);
            m1 = __builtin_elementwise_fma(Mp[1][5], f5, m1);
            m2 = __builtin_elementwise_fma(Mp[2][5], f5, m2);
            m3 = __builtin_elementwise_fma(Mp[3][5], f5, m3);
            m0 = __builtin_elementwise_fma(Mp[0][6], f6, m0);
            m1 = __builtin_elementwise_fma(Mp[1][6], f6, m1);
            m2 = __builtin_elementwise_fma(Mp[2][6], f6, m2);
            m3 = __builtin_elementwise_fma(Mp[3][6], f6, m3);
            m0 = __builtin_elementwise_fma(Mp[0][7], f7, m0);
            m1 = __builtin_elementwise_fma(Mp[1][7], f7, m1);
            m2 = __builtin_elementwise_fma(Mp[2][7], f7, m2);
            m3 = __builtin_elementwise_fma(Mp[3][7], f7, m3);
            const float R0 = m0.x + m0.y;
            const float R1 = m1.x + m1.y;
            const float R2 = m2.x + m2.y;
            const float R3 = m3.x + m3.y;
            const float R = R0 + dpp_f<0xB1>(R1) + dpp_f<0x4E>(R2) + dpp_f<0x1B>(R3);
            A = fmaf(dt, R, A);

            v2f uv = __builtin_elementwise_fma(W1up[0], (v2f){una.x, una.y}, (v2f){0.f, 0.f});
            uv = __builtin_elementwise_fma(W1up[1], (v2f){una.z, una.w}, uv);
            uv = __builtin_elementwise_fma(W1up[2], (v2f){unb.x, unb.y}, uv);
            uacc = uv.x + uv.y + fmaf(W1u6, unb.z, b1r);
        };

        for (int cb = 0; cb <= NCHUNK; ++cb) {
            const int need_staged = (cb + 2 < NCHUNK + 1) ? cb + 2 : NCHUNK + 1;
            while (__hip_atomic_load(&flg[1], __ATOMIC_ACQUIRE,
                                     __HIP_MEMORY_SCOPE_WORKGROUP) < need_staged)
                __builtin_amdgcn_s_sleep(1);
            while (__hip_atomic_load(&flg[2], __ATOMIC_ACQUIRE,
                                     __HIP_MEMORY_SCOPE_WORKGROUP) < cb - 1)
                __builtin_amdgcn_s_sleep(1);
            const int zbase = (cb & 1) * ZH;
            const int ub = (cb % 3) * 512;
            if (cb < NCHUNK) {
                const int un = ((cb + 1) % 3) * 512;
#pragma unroll 8
                for (int li = 0; li < 64; ++li) {
                    const int uoff = (li < 63) ? ub + (li + 1) * 8 : un;
                    step(li, uoff, zbase);
                }
            } else {
                for (int li = 0; li < TAIL; ++li) step(li, ub + (li + 1) * 8, zbase);
            }
            __hip_atomic_store(&flg[0], cb + 1, __ATOMIC_RELEASE,
                               __HIP_MEMORY_SCOPE_WORKGROUP);
        }

        // ---- final state: h(T) = h0 + dt*W3@zacc + T*dt*b3 ----
        zbuf[lane] = zacc;
        float4 za[16];
#pragma unroll
        for (int qq = 0; qq < 16; ++qq) za[qq] = *(const float4*)&zbuf[qq * 4];
        const int row = lane & 15;
        const float* w3r = W3 + row * 64;
        float h0a = 0.f, h1a = 0.f;
#pragma unroll
        for (int qq = 0; qq < 16; ++qq) {
            h0a = fmaf(w3r[4 * qq + 0], za[qq].x, h0a);
            h1a = fmaf(w3r[4 * qq + 1], za[qq].y, h1a);
            h0a = fmaf(w3r[4 * qq + 2], za[qq].z, h0a);
            h1a = fmaf(w3r[4 * qq + 3], za[qq].w, h1a);
        }
        const float hT = h0[row] + dt * (h0a + h1a) + (float)T_STEPS * dt * b3[row];
        if (lane < 16) out[3 * T_STEPS + lane] = hT;
    } else {
        // =================== wave 1: staging + batched readouts =============
        for (int cb = 0; cb <= NCHUNK; ++cb) {
            while (__hip_atomic_load(&flg[0], __ATOMIC_ACQUIRE,
                                     __HIP_MEMORY_SCOPE_WORKGROUP) < cb + 1)
                __builtin_amdgcn_s_sleep(8);
            if (cb + 3 <= NCHUNK) {
                const int dst = ((cb + 3) % 3) * 512;
                const int base = (cb + 3) * 448;
#pragma unroll
                for (int r = 0; r < UDIM; ++r) {
                    int idx = base + r * 64 + lane;
                    if (idx > T_STEPS * UDIM - 1) idx = T_STEPS * UDIM - 1;
                    const float val = U[idx];
                    int flat = r * 64 + lane;
                    int s = flat / 7, c = flat % 7;
                    ubuf[dst + s * 8 + c] = val;
                }
                __hip_atomic_store(&flg[1], cb + 4, __ATOMIC_RELEASE,
                                   __HIP_MEMORY_SCOPE_WORKGROUP);
            }
            // ---- batched readouts for chunk cb ----
            const float* zr = &zhist[(cb & 1) * ZH + lane * ZSTR];
            v2f sd = {0.f, 0.f}, st = {0.f, 0.f}, sc = {0.f, 0.f};
#pragma unroll
            for (int qq = 0; qq < 32; ++qq) {
                v2f zv = *(const v2f*)&zr[2 * qq];
                sd = __builtin_elementwise_fma(*(const v2f*)&cbuf[2 * qq],       zv, sd);
                st = __builtin_elementwise_fma(*(const v2f*)&cbuf[64 + 2 * qq],  zv, st);
                sc = __builtin_elementwise_fma(*(const v2f*)&cbuf[128 + 2 * qq], zv, sc);
            }
            float Sd = sd.x + sd.y, St = st.x + st.y, Sc = sc.x + sc.y;
            const float oD = Sd, oT = St, oC = Sc;
#pragma unroll
            for (int dl = 1; dl < 64; dl <<= 1) {
                float ud = __shfl_up(Sd, dl, 64);
                float ut = __shfl_up(St, dl, 64);
                float uc = __shfl_up(Sc, dl, 64);
                if (lane >= dl) { Sd += ud; St += ut; Sc += uc; }
            }
            const int t = cb * 64 + lane;
            if (t < T_STEPS) {
                const float fl = (float)lane;
                out[t]               = fmaf(dt, Sd - oD, rchD) + fl * rbD;
                out[T_STEPS + t]     = fmaf(dt, St - oT, rchT) + fl * rbT;
                out[2 * T_STEPS + t] = fmaf(dt, Sc - oC, rchC) + fl * rbC;
            }
            rchD = fmaf(dt, readlane_f(Sd, 63), rchD) + 64.f * rbD;
            rchT = fmaf(dt, readlane_f(St, 63), rchT) + 64.f * rbT;
            rchC = fmaf(dt, readlane_f(Sc, 63), rchC) + 64.f * rbC;
            __hip_atomic_store(&flg[2], cb + 1, __ATOMIC_RELEASE,
                               __HIP_MEMORY_SCOPE_WORKGROUP);
        }
    }
}

extern "C" void kernel_launch(void* const* d_in, const int* in_sizes, int n_in,
                              void* d_out, int out_size, void* d_ws, size_t ws_size,
                              hipStream_t stream) {
    const float* U  = (const float*)d_in[0];
    const float* W1 = (const float*)d_in[1];
    const float* b1 = (const float*)d_in[2];
    const float* W2 = (const float*)d_in[3];
    const float* b2 = (const float*)d_in[4];
    const float* W3 = (const float*)d_in[5];
    const float* b3 = (const float*)d_in[6];
    const float* wd = (const float*)d_in[7];
    const float* bd = (const float*)d_in[8];
    const float* wt = (const float*)d_in[9];
    const float* bt = (const float*)d_in[10];
    const float* wc = (const float*)d_in[11];
    const float* bc = (const float*)d_in[12];
    const float* h0 = (const float*)d_in[13];
    (void)in_sizes; (void)n_in; (void)out_size; (void)d_ws; (void)ws_size;

    node_scan<<<dim3(1), dim3(128), 0, stream>>>(U, W1, b1, W2, b2, W3, b3,
                                                 wd, bd, wt, bt, wc, bc, h0,
                                                 (float*)d_out);
}

// Round 13
// 26406.216 us; speedup vs baseline: 1.9506x; 1.0531x over previous
//
#include <hip/hip_runtime.h>

typedef float v2f __attribute__((ext_vector_type(2)));

#define T_STEPS 100000
#define UDIM 7
#define NCHUNK 1562   /* full 64-step chunks */
#define TAIL 32       /* 100000 - 1562*64 */
#define ZSTR 68       /* zhist row stride (floats) */
#define ZH (64 * ZSTR)
#define UROWS 65      /* 64 steps + duplicated row0 of next chunk */
#define UAB (UROWS * 64)

__device__ __forceinline__ float tanh_fast(float x) {
    float e = __expf(2.0f * x);
    return 1.0f - 2.0f * __builtin_amdgcn_rcpf(e + 1.0f);
}

__device__ __forceinline__ float readlane_f(float v, int l) {
    return __int_as_float(__builtin_amdgcn_readlane(__float_as_int(v), l));
}

template <int CTRL>
__device__ __forceinline__ float dpp_f(float v) {
    return __int_as_float(__builtin_amdgcn_update_dpp(
        0, __float_as_int(v), CTRL, 0xF, 0xF, true));
}

__global__ __launch_bounds__(128) __attribute__((amdgpu_waves_per_eu(1, 1)))
void node_scan(const float* __restrict__ U,
               const float* __restrict__ W1, const float* __restrict__ b1,
               const float* __restrict__ W2, const float* __restrict__ b2,
               const float* __restrict__ W3, const float* __restrict__ b3,
               const float* __restrict__ wd, const float* __restrict__ bd,
               const float* __restrict__ wt, const float* __restrict__ bt,
               const float* __restrict__ wc, const float* __restrict__ bc,
               const float* __restrict__ h0,
               float* __restrict__ out)
{
    const int tid  = threadIdx.x;
    const int wv   = tid >> 6;               // 0 = compute wave, 1 = service wave
    const int lane = tid & 63;
    const int g = lane >> 2;                 // output group (0..15)
    const int q = lane & 3;                  // z-segment this lane reads (0..3)
    const float dt = (float)(5.0 / 60.0);

    __shared__ __align__(16) float zbuf[64];          // z1 broadcast / vacc scatter
    __shared__ __align__(16) float ubuf[3 * 512];     // u chunks (wave1-only)
    __shared__ __align__(16) float zhist[2 * ZH];     // z2 history, double-buffered
    __shared__ __align__(16) float cbuf[3 * 64];      // readout functionals (wave1)
    __shared__ __align__(16) float uab[2 * UAB];      // uacc tables, double-buffered
    __shared__ __align__(16) float Msh[64 * 64];      // M staging (init only)
    __shared__ int flg[4];                            // 0=w0 done,1=uacc ready,2=batch done

    if (tid == 0) { flg[0] = 0; flg[1] = 0; flg[2] = 0; }

    // wave0 regs
    float w1h[16]; float b2r = 0.f;
    v2f W2p[4][8];
    // wave1 regs
    v2f W1up[3]; float W1u6 = 0.f, b1l = 0.f;
    float rbD = 0.f, rbT = 0.f, rbC = 0.f, rchD = 0.f, rchT = 0.f, rchC = 0.f;

    if (wv == 0) {
#pragma unroll
        for (int j = 0; j < 16; ++j) w1h[j] = W1[lane * 23 + j];
        b2r = b2[lane];
#pragma unroll
        for (int d = 0; d < 4; ++d) {
            const int orow = (g << 2) | (q ^ d);
            const float* w2r = W2 + orow * 64 + q * 16;
#pragma unroll
            for (int j = 0; j < 8; ++j) W2p[d][j] = (v2f){ w2r[2 * j], w2r[2 * j + 1] };
        }
        for (int c = 0; c < 64; ++c) {
            float acc = 0.f;
#pragma unroll
            for (int k = 0; k < 16; ++k) acc = fmaf(w1h[k], W3[k * 64 + c], acc);
            Msh[lane * 64 + c] = acc;
        }
    } else {
        // u-part weights for this lane's row
#pragma unroll
        for (int j = 0; j < 3; ++j) {
            W1up[j].x = W1[lane * 23 + 16 + 2 * j];
            W1up[j].y = W1[lane * 23 + 17 + 2 * j];
        }
        W1u6 = W1[lane * 23 + 22];
        b1l = b1[lane];
        // readout functionals c = W3^T w → LDS
        float cd = 0.f, ct = 0.f, cc = 0.f;
        for (int k = 0; k < 16; ++k) {
            const float w3v = W3[k * 64 + lane];
            cd = fmaf(wd[k], w3v, cd);
            ct = fmaf(wt[k], w3v, ct);
            cc = fmaf(wc[k], w3v, cc);
        }
        cbuf[lane] = cd; cbuf[64 + lane] = ct; cbuf[128 + lane] = cc;
        rchD = bd[0]; rchT = bt[0]; rchC = bc[0];
        for (int k = 0; k < 16; ++k) {
            rbD = fmaf(wd[k], b3[k], rbD);  rchD = fmaf(wd[k], h0[k], rchD);
            rbT = fmaf(wt[k], b3[k], rbT);  rchT = fmaf(wt[k], h0[k], rchT);
            rbC = fmaf(wc[k], b3[k], rbC);  rchC = fmaf(wc[k], h0[k], rchC);
        }
        rbD *= dt; rbT *= dt; rbC *= dt;
        // stage u chunks 0,1,2
#pragma unroll
        for (int c = 0; c < 3; ++c) {
            const int base = c * 448, dst = c * 512;
#pragma unroll
            for (int r = 0; r < UDIM; ++r) {
                int flat = r * 64 + lane;
                int s = flat / 7, cc2 = flat % 7;
                ubuf[dst + s * 8 + cc2] = U[base + flat];
            }
            ubuf[dst + lane * 8 + 7] = 0.f;
        }
    }
    __syncthreads();

    if (wv == 0) {
        v2f Mp[4][8];
#pragma unroll
        for (int d = 0; d < 4; ++d) {
            const int orow = (g << 2) | (q ^ d);
            const float* mr = Msh + orow * 64 + q * 16;
#pragma unroll
            for (int j = 0; j < 8; ++j) Mp[d][j] = (v2f){ mr[2 * j], mr[2 * j + 1] };
        }
        float m3od = 0.f;
#pragma unroll
        for (int k = 0; k < 16; ++k) m3od = fmaf(w1h[k], b3[k], m3od);
        float A = 0.f;
        for (int k = 0; k < 16; ++k) A = fmaf(w1h[k], h0[k], A);

        while (__hip_atomic_load(&flg[1], __ATOMIC_ACQUIRE,
                                 __HIP_MEMORY_SCOPE_WORKGROUP) < 1)
            __builtin_amdgcn_s_sleep(1);
        float uacc = uab[lane];                        // chunk0 row0

        auto step = [&](int li, int ub4, int zb4) {
            const float z1 = tanh_fast(A + uacc);
            zbuf[lane] = z1;
            float4 s0 = *(const float4*)&zbuf[q * 16 + 0];
            float4 s1 = *(const float4*)&zbuf[q * 16 + 4];
            float4 s2 = *(const float4*)&zbuf[q * 16 + 8];
            float4 s3 = *(const float4*)&zbuf[q * 16 + 12];
            const float uacc_next = uab[ub4 + (li + 1) * 64 + lane];

            v2f e0 = {s0.x, s0.y}, e1 = {s0.z, s0.w};
            v2f e2 = {s1.x, s1.y}, e3 = {s1.z, s1.w};
            v2f e4 = {s2.x, s2.y}, e5 = {s2.z, s2.w};
            v2f e6 = {s3.x, s3.y}, e7 = {s3.z, s3.w};
            v2f c0 = {b2r, 0.f}, c1 = {0.f, 0.f}, c2 = {0.f, 0.f}, c3 = {0.f, 0.f};
            c0 = __builtin_elementwise_fma(W2p[0][0], e0, c0);
            c1 = __builtin_elementwise_fma(W2p[1][0], e0, c1);
            c2 = __builtin_elementwise_fma(W2p[2][0], e0, c2);
            c3 = __builtin_elementwise_fma(W2p[3][0], e0, c3);
            c0 = __builtin_elementwise_fma(W2p[0][1], e1, c0);
            c1 = __builtin_elementwise_fma(W2p[1][1], e1, c1);
            c2 = __builtin_elementwise_fma(W2p[2][1], e1, c2);
            c3 = __builtin_elementwise_fma(W2p[3][1], e1, c3);
            c0 = __builtin_elementwise_fma(W2p[0][2], e2, c0);
            c1 = __builtin_elementwise_fma(W2p[1][2], e2, c1);
            c2 = __builtin_elementwise_fma(W2p[2][2], e2, c2);
            c3 = __builtin_elementwise_fma(W2p[3][2], e2, c3);
            c0 = __builtin_elementwise_fma(W2p[0][3], e3, c0);
            c1 = __builtin_elementwise_fma(W2p[1][3], e3, c1);
            c2 = __builtin_elementwise_fma(W2p[2][3], e3, c2);
            c3 = __builtin_elementwise_fma(W2p[3][3], e3, c3);
            c0 = __builtin_elementwise_fma(W2p[0][4], e4, c0);
            c1 = __builtin_elementwise_fma(W2p[1][4], e4, c1);
            c2 = __builtin_elementwise_fma(W2p[2][4], e4, c2);
            c3 = __builtin_elementwise_fma(W2p[3][4], e4, c3);
            c0 = __builtin_elementwise_fma(W2p[0][5], e5, c0);
            c1 = __builtin_elementwise_fma(W2p[1][5], e5, c1);
            c2 = __builtin_elementwise_fma(W2p[2][5], e5, c2);
            c3 = __builtin_elementwise_fma(W2p[3][5], e5, c3);
            c0 = __builtin_elementwise_fma(W2p[0][6], e6, c0);
            c1 = __builtin_elementwise_fma(W2p[1][6], e6, c1);
            c2 = __builtin_elementwise_fma(W2p[2][6], e6, c2);
            c3 = __builtin_elementwise_fma(W2p[3][6], e6, c3);
            c0 = __builtin_elementwise_fma(W2p[0][7], e7, c0);
            c1 = __builtin_elementwise_fma(W2p[1][7], e7, c1);
            c2 = __builtin_elementwise_fma(W2p[2][7], e7, c2);
            c3 = __builtin_elementwise_fma(W2p[3][7], e7, c3);
            const float P0 = c0.x + c0.y;
            const float P1 = c1.x + c1.y;
            const float P2 = c2.x + c2.y;
            const float P3 = c3.x + c3.y;
            const float Q = P0 + dpp_f<0xB1>(P1) + dpp_f<0x4E>(P2) + dpp_f<0x1B>(P3);
            const float z2 = tanh_fast(Q);
            zhist[zb4 + li * ZSTR + lane] = z2;
            const float* zrow = &zhist[zb4 + li * ZSTR + q * 16];
            float4 t0 = *(const float4*)&zrow[0];
            float4 t1 = *(const float4*)&zrow[4];
            float4 t2 = *(const float4*)&zrow[8];
            float4 t3 = *(const float4*)&zrow[12];

            v2f f0 = {t0.x, t0.y}, f1 = {t0.z, t0.w};
            v2f f2 = {t1.x, t1.y}, f3 = {t1.z, t1.w};
            v2f f4 = {t2.x, t2.y}, f5 = {t2.z, t2.w};
            v2f f6 = {t3.x, t3.y}, f7 = {t3.z, t3.w};
            v2f m0 = {m3od, 0.f}, m1 = {0.f, 0.f}, m2 = {0.f, 0.f}, m3 = {0.f, 0.f};
            m0 = __builtin_elementwise_fma(Mp[0][0], f0, m0);
            m1 = __builtin_elementwise_fma(Mp[1][0], f0, m1);
            m2 = __builtin_elementwise_fma(Mp[2][0], f0, m2);
            m3 = __builtin_elementwise_fma(Mp[3][0], f0, m3);
            m0 = __builtin_elementwise_fma(Mp[0][1], f1, m0);
            m1 = __builtin_elementwise_fma(Mp[1][1], f1, m1);
            m2 = __builtin_elementwise_fma(Mp[2][1], f1, m2);
            m3 = __builtin_elementwise_fma(Mp[3][1], f1, m3);
            m0 = __builtin_elementwise_fma(Mp[0][2], f2, m0);
            m1 = __builtin_elementwise_fma(Mp[1][2], f2, m1);
            m2 = __builtin_elementwise_fma(Mp[2][2], f2, m2);
            m3 = __builtin_elementwise_fma(Mp[3][2], f2, m3);
            m0 = __builtin_elementwise_fma(Mp[0][3], f3, m0);
            m1 = __builtin_elementwise_fma(Mp[1][3], f3, m1);
            m2 = __builtin_elementwise_fma(Mp[2][3], f3, m2);
            m3 = __builtin_elementwise_fma(Mp[3][3], f3, m3);
            m0 = __builtin_elementwise_fma(Mp[0][4], f4, m0);
            m1 = __builtin_elementwise_fma(Mp[1][4], f4, m1);
            m2 = __builtin_elementwise_fma(Mp[2][4], f4, m2);
            m3 = __builtin_elementwise_fma(Mp[3][4], f4, m3);
            m0 = __builtin_elementwise_fma(Mp[0][5], f5, m0);
            m1 = __builtin_elementwise_fma(Mp[1][5], f5, m1);
            m2 = __builtin_elementwise_fma(Mp[2][5], f5, m2);
            m3 = __builtin_elementwise_fma(Mp[3][5], f5, m3);
            m0 = __builtin_elementwise_fma(Mp[0][6], f6, m0);
            m1 = __builtin_elementwise_fma(Mp[1][6], f6, m1);
            m2 = __builtin_elementwise_fma(Mp[2][6], f6, m2);
            m3 = __builtin_elementwise_fma(Mp[3][6], f6, m3);
            m0 = __builtin_elementwise_fma(Mp[0][7], f7, m0);
            m1 = __builtin_elementwise_fma(Mp[1][7], f7, m1);
            m2 = __builtin_elementwise_fma(Mp[2][7], f7, m2);
            m3 = __builtin_elementwise_fma(Mp[3][7], f7, m3);
            const float R0 = m0.x + m0.y;
            const float R1 = m1.x + m1.y;
            const float R2 = m2.x + m2.y;
            const float R3 = m3.x + m3.y;
            const float R = R0 + dpp_f<0xB1>(R1) + dpp_f<0x4E>(R2) + dpp_f<0x1B>(R3);
            A = fmaf(dt, R, A);
            uacc = uacc_next;
        };

        for (int cb = 0; cb <= NCHUNK; ++cb) {
            while (__hip_atomic_load(&flg[1], __ATOMIC_ACQUIRE,
                                     __HIP_MEMORY_SCOPE_WORKGROUP) < cb + 1)
                __builtin_amdgcn_s_sleep(1);
            while (__hip_atomic_load(&flg[2], __ATOMIC_ACQUIRE,
                                     __HIP_MEMORY_SCOPE_WORKGROUP) < cb - 1)
                __builtin_amdgcn_s_sleep(1);
            const int zb4 = (cb & 1) * ZH;
            const int ub4 = (cb & 1) * UAB;
            if (cb < NCHUNK) {
#pragma unroll 8
                for (int li = 0; li < 64; ++li) step(li, ub4, zb4);
            } else {
                for (int li = 0; li < TAIL; ++li) step(li, ub4, zb4);
            }
            __hip_atomic_store(&flg[0], cb + 1, __ATOMIC_RELEASE,
                               __HIP_MEMORY_SCOPE_WORKGROUP);
        }
    } else {
        // =================== wave 1: staging + uacc + readouts ==============
        float vacc = 0.f;   // per-component z2 sum (for h(T))

        auto uacc_chunk = [&](int c) {
            const int par = (c & 1) * UAB;
            const int src = (c % 3) * 512;
            const int nxt = ((c + 1) % 3) * 512;
            for (int li = 0; li < UROWS; ++li) {
                const int uo = (li < 64) ? src + li * 8 : nxt;
                float4 ua = *(const float4*)&ubuf[uo];
                float4 ub = *(const float4*)&ubuf[uo + 4];
                v2f uv = __builtin_elementwise_fma(W1up[0], (v2f){ua.x, ua.y}, (v2f){0.f, 0.f});
                uv = __builtin_elementwise_fma(W1up[1], (v2f){ua.z, ua.w}, uv);
                uv = __builtin_elementwise_fma(W1up[2], (v2f){ub.x, ub.y}, uv);
                uab[par + li * 64 + lane] = uv.x + uv.y + fmaf(W1u6, ub.z, b1l);
            }
        };
        uacc_chunk(0);
        uacc_chunk(1);
        __hip_atomic_store(&flg[1], 2, __ATOMIC_RELEASE,
                           __HIP_MEMORY_SCOPE_WORKGROUP);

        for (int cb = 0; cb <= NCHUNK; ++cb) {
            while (__hip_atomic_load(&flg[0], __ATOMIC_ACQUIRE,
                                     __HIP_MEMORY_SCOPE_WORKGROUP) < cb + 1)
                __builtin_amdgcn_s_sleep(8);
            if (cb + 3 <= NCHUNK) {
                const int dst = ((cb + 3) % 3) * 512;
                const int base = (cb + 3) * 448;
#pragma unroll
                for (int r = 0; r < UDIM; ++r) {
                    int idx = base + r * 64 + lane;
                    if (idx > T_STEPS * UDIM - 1) idx = T_STEPS * UDIM - 1;
                    const float val = U[idx];
                    int flat = r * 64 + lane;
                    int s = flat / 7, c = flat % 7;
                    ubuf[dst + s * 8 + c] = val;
                }
            }
            if (cb + 2 <= NCHUNK) {
                uacc_chunk(cb + 2);
                __hip_atomic_store(&flg[1], cb + 3, __ATOMIC_RELEASE,
                                   __HIP_MEMORY_SCOPE_WORKGROUP);
            }
            // ---- batched readouts + vacc for chunk cb ----
            const int zb4 = (cb & 1) * ZH;
            const int ns = (cb == NCHUNK) ? TAIL : 64;
            float colsum = 0.f;
            for (int li = 0; li < ns; ++li) colsum += zhist[zb4 + li * ZSTR + lane];
            vacc += colsum;

            const float* zr = &zhist[zb4 + lane * ZSTR];
            v2f sd = {0.f, 0.f}, st = {0.f, 0.f}, sc = {0.f, 0.f};
#pragma unroll
            for (int qq = 0; qq < 32; ++qq) {
                v2f zv = *(const v2f*)&zr[2 * qq];
                sd = __builtin_elementwise_fma(*(const v2f*)&cbuf[2 * qq],       zv, sd);
                st = __builtin_elementwise_fma(*(const v2f*)&cbuf[64 + 2 * qq],  zv, st);
                sc = __builtin_elementwise_fma(*(const v2f*)&cbuf[128 + 2 * qq], zv, sc);
            }
            float Sd = sd.x + sd.y, St = st.x + st.y, Sc = sc.x + sc.y;
            const float oD = Sd, oT = St, oC = Sc;
#pragma unroll
            for (int dl = 1; dl < 64; dl <<= 1) {
                float ud = __shfl_up(Sd, dl, 64);
                float ut = __shfl_up(St, dl, 64);
                float uc = __shfl_up(Sc, dl, 64);
                if (lane >= dl) { Sd += ud; St += ut; Sc += uc; }
            }
            const int t = cb * 64 + lane;
            if (t < T_STEPS) {
                const float fl = (float)lane;
                out[t]               = fmaf(dt, Sd - oD, rchD) + fl * rbD;
                out[T_STEPS + t]     = fmaf(dt, St - oT, rchT) + fl * rbT;
                out[2 * T_STEPS + t] = fmaf(dt, Sc - oC, rchC) + fl * rbC;
            }
            rchD = fmaf(dt, readlane_f(Sd, 63), rchD) + 64.f * rbD;
            rchT = fmaf(dt, readlane_f(St, 63), rchT) + 64.f * rbT;
            rchC = fmaf(dt, readlane_f(Sc, 63), rchC) + 64.f * rbC;
            __hip_atomic_store(&flg[2], cb + 1, __ATOMIC_RELEASE,
                               __HIP_MEMORY_SCOPE_WORKGROUP);
        }

        // ---- h(T) = h0 + dt*W3@vacc + T*dt*b3 (wave0 fully done by now) ----
        zbuf[lane] = vacc;
        if (lane < 16) {
            const float* w3r = W3 + lane * 64;
            float h0a = 0.f, h1a = 0.f;
#pragma unroll
            for (int qq = 0; qq < 16; ++qq) {
                float4 za = *(const float4*)&zbuf[qq * 4];
                h0a = fmaf(w3r[4 * qq + 0], za.x, h0a);
                h1a = fmaf(w3r[4 * qq + 1], za.y, h1a);
                h0a = fmaf(w3r[4 * qq + 2], za.z, h0a);
                h1a = fmaf(w3r[4 * qq + 3], za.w, h1a);
            }
            out[3 * T_STEPS + lane] =
                h0[lane] + dt * (h0a + h1a) + (float)T_STEPS * dt * b3[lane];
        }
    }
}

extern "C" void kernel_launch(void* const* d_in, const int* in_sizes, int n_in,
                              void* d_out, int out_size, void* d_ws, size_t ws_size,
                              hipStream_t stream) {
    const float* U  = (const float*)d_in[0];
    const float* W1 = (const float*)d_in[1];
    const float* b1 = (const float*)d_in[2];
    const float* W2 = (const float*)d_in[3];
    const float* b2 = (const float*)d_in[4];
    const float* W3 = (const float*)d_in[5];
    const float* b3 = (const float*)d_in[6];
    const float* wd = (const float*)d_in[7];
    const float* bd = (const float*)d_in[8];
    const float* wt = (const float*)d_in[9];
    const float* bt = (const float*)d_in[10];
    const float* wc = (const float*)d_in[11];
    const float* bc = (const float*)d_in[12];
    const float* h0 = (const float*)d_in[13];
    (void)in_sizes; (void)n_in; (void)out_size; (void)d_ws; (void)ws_size;

    node_scan<<<dim3(1), dim3(128), 0, stream>>>(U, W1, b1, W2, b2, W3, b3,
                                                 wd, bd, wt, bt, wc, bc, h0,
                                                 (float*)d_out);
}